// Round 1
// baseline (1598.351 us; speedup 1.0000x reference)
//
#include <hip/hip_runtime.h>
#include <math.h>

#define NG 64
#define HID 64

// ---- degree count (edges only; +1 self-loop added in dinv) ----
__global__ void k_deg(const int* __restrict__ dst, int E, int* __restrict__ deg) {
    int i = blockIdx.x * blockDim.x + threadIdx.x;
    if (i < E) atomicAdd(deg + dst[i], 1);
}

__global__ void k_dinv(const int* __restrict__ deg, float* __restrict__ dinv, int n) {
    int i = blockIdx.x * blockDim.x + threadIdx.x;
    if (i < n) dinv[i] = 1.0f / sqrtf((float)deg[i] + 1.0f);
}

// ---- GEMM: out[n,64] = (relu?)(A[n,K]) @ W[K,64]; one row per wave ----
template<int K, bool RELU>
__global__ __launch_bounds__(256) void k_gemm(const float* __restrict__ A,
                                              const float* __restrict__ W,
                                              float* __restrict__ out, int n) {
    __shared__ float Ws[K * HID];
    for (int i = threadIdx.x; i < K * HID; i += 256) Ws[i] = W[i];
    __syncthreads();
    const int wave = threadIdx.x >> 6, lane = threadIdx.x & 63;
    for (int row = blockIdx.x * 4 + wave; row < n; row += gridDim.x * 4) {
        const float* a = A + (size_t)row * K;
        float acc = 0.f;
#pragma unroll
        for (int k4 = 0; k4 < K / 4; ++k4) {
            float4 v = *(const float4*)(a + k4 * 4);
            if (RELU) {
                v.x = fmaxf(v.x, 0.f); v.y = fmaxf(v.y, 0.f);
                v.z = fmaxf(v.z, 0.f); v.w = fmaxf(v.w, 0.f);
            }
            acc = fmaf(v.x, Ws[(k4 * 4 + 0) * HID + lane], acc);
            acc = fmaf(v.y, Ws[(k4 * 4 + 1) * HID + lane], acc);
            acc = fmaf(v.z, Ws[(k4 * 4 + 2) * HID + lane], acc);
            acc = fmaf(v.w, Ws[(k4 * 4 + 3) * HID + lane], acc);
        }
        out[(size_t)row * HID + lane] = acc;
    }
}

// ---- out[i,:] = b + h[i,:]*dinv[i]^2  (bias + self-loop term) ----
__global__ void k_init(const float* __restrict__ h, const float* __restrict__ dinv,
                       const float* __restrict__ b, float* __restrict__ out, int n) {
    int i = blockIdx.x * blockDim.x + threadIdx.x;  // over n*16 (float4 granules)
    if (i >= n * 16) return;
    int row = i >> 4, c4 = (i & 15) << 2;
    float di = dinv[row];
    float s = di * di;
    float4 hv = *(const float4*)(h + (size_t)row * HID + c4);
    float4 bv = *(const float4*)(b + c4);
    float4 o;
    o.x = fmaf(hv.x, s, bv.x); o.y = fmaf(hv.y, s, bv.y);
    o.z = fmaf(hv.z, s, bv.z); o.w = fmaf(hv.w, s, bv.w);
    *(float4*)(out + (size_t)row * HID + c4) = o;
}

// ---- edge scatter: out[dst,:] += h[src,:] * dinv[src]*dinv[dst] ----
__global__ __launch_bounds__(256) void k_edges(const float* __restrict__ h,
                                               const int* __restrict__ src,
                                               const int* __restrict__ dst,
                                               const float* __restrict__ dinv,
                                               float* __restrict__ out, int E) {
    int i = blockIdx.x * blockDim.x + threadIdx.x;  // E*16 threads, float4 each
    int e = i >> 4;
    if (e >= E) return;
    int c4 = (i & 15) << 2;
    int s = src[e], d = dst[e];
    float norm = dinv[s] * dinv[d];
    float4 v = *(const float4*)(h + (size_t)s * HID + c4);
    float* o = out + (size_t)d * HID + c4;
    atomicAdd(o + 0, v.x * norm);
    atomicAdd(o + 1, v.y * norm);
    atomicAdd(o + 2, v.z * norm);
    atomicAdd(o + 3, v.w * norm);
}

// ---- mean pool per graph (batch sorted): block per graph, binary search ----
__global__ __launch_bounds__(256) void k_pool(const float* __restrict__ h,
                                              const int* __restrict__ batch,
                                              float* __restrict__ gm, int n) {
    int g = blockIdx.x;
    int lo = 0, hi = n;
    while (lo < hi) { int m = (lo + hi) >> 1; if (batch[m] < g) lo = m + 1; else hi = m; }
    int lo2 = lo, hi2 = n;
    while (lo2 < hi2) { int m = (lo2 + hi2) >> 1; if (batch[m] < g + 1) lo2 = m + 1; else hi2 = m; }
    int col = threadIdx.x & 63, seg = threadIdx.x >> 6;
    float acc = 0.f;
    for (int r = lo + seg; r < lo2; r += 4)
        acc += fmaxf(h[(size_t)r * HID + col], 0.f);
    __shared__ float red[4][HID];
    red[seg][col] = acc;
    __syncthreads();
    if (seg == 0) {
        float ssum = red[0][col] + red[1][col] + red[2][col] + red[3][col];
        float cnt = (float)(lo2 - lo);
        gm[g * HID + col] = ssum / fmaxf(cnt, 1.0f);
    }
}

// ---- MLP head: out[g] = relu(gm[g]@Wc1+bc1) @ Wc2 + bc2 ----
__global__ void k_head(const float* __restrict__ gm, const float* __restrict__ Wc1,
                       const float* __restrict__ bc1, const float* __restrict__ Wc2,
                       const float* __restrict__ bc2, float* __restrict__ outp) {
    int g = threadIdx.x;
    if (g >= NG) return;
    float o = bc2[0];
    for (int j = 0; j < 32; ++j) {
        float z = bc1[j];
        for (int k = 0; k < HID; ++k) z = fmaf(gm[g * HID + k], Wc1[k * 32 + j], z);
        o = fmaf(fmaxf(z, 0.f), Wc2[j], o);
    }
    outp[g] = o;
}

extern "C" void kernel_launch(void* const* d_in, const int* in_sizes, int n_in,
                              void* d_out, int out_size, void* d_ws, size_t ws_size,
                              hipStream_t stream) {
    const float* x    = (const float*)d_in[0];
    const int*   ei   = (const int*)d_in[1];
    const int*   batch= (const int*)d_in[2];
    const float* W1   = (const float*)d_in[3];
    const float* b1   = (const float*)d_in[4];
    const float* W2   = (const float*)d_in[5];
    const float* b2   = (const float*)d_in[6];
    const float* Wc1  = (const float*)d_in[7];
    const float* bc1  = (const float*)d_in[8];
    const float* Wc2  = (const float*)d_in[9];
    const float* bc2  = (const float*)d_in[10];

    const int E = in_sizes[1] / 2;
    const int n = in_sizes[0] / 128;   // 50000 nodes
    const int* srcp = ei;
    const int* dstp = ei + E;

    char* ws = (char*)d_ws;
    auto alloc = [&](size_t bytes) {
        char* p = ws;
        ws += (bytes + 255) & ~(size_t)255;
        return p;
    };
    int*   deg  = (int*)  alloc((size_t)n * 4);
    float* dinv = (float*)alloc((size_t)n * 4);
    float* bufA = (float*)alloc((size_t)n * HID * 4);  // h1, then h2
    float* bufB = (float*)alloc((size_t)n * HID * 4);  // out1, then out2
    float* gm   = (float*)alloc((size_t)NG * HID * 4);

    hipMemsetAsync(deg, 0, (size_t)n * 4, stream);
    k_deg <<<(E + 255) / 256, 256, 0, stream>>>(dstp, E, deg);
    k_dinv<<<(n + 255) / 256, 256, 0, stream>>>(deg, dinv, n);

    // Layer 1
    k_gemm<128, false><<<512, 256, 0, stream>>>(x, W1, bufA, n);
    k_init <<<(n * 16 + 255) / 256, 256, 0, stream>>>(bufA, dinv, b1, bufB, n);
    k_edges<<<(E * 16 + 255) / 256, 256, 0, stream>>>(bufA, srcp, dstp, dinv, bufB, E);

    // Layer 2 (relu of out1 fused into the GEMM's A-load)
    k_gemm<64, true><<<512, 256, 0, stream>>>(bufB, W2, bufA, n);
    k_init <<<(n * 16 + 255) / 256, 256, 0, stream>>>(bufA, dinv, b2, bufB, n);
    k_edges<<<(E * 16 + 255) / 256, 256, 0, stream>>>(bufA, srcp, dstp, dinv, bufB, E);

    // Pool (relu fused) + head
    k_pool<<<NG, 256, 0, stream>>>(bufB, batch, gm, n);
    k_head<<<1, 64, 0, stream>>>(gm, Wc1, bc1, Wc2, bc2, (float*)d_out);
}

// Round 2
// 386.927 us; speedup vs baseline: 4.1309x; 4.1309x over previous
//
#include <hip/hip_runtime.h>
#include <math.h>

#define NG 64
#define HID 64

// ---- degree count (in-degree from edges; self-loop added in dinv) ----
__global__ void k_deg(const int* __restrict__ dst, int E, int* __restrict__ deg) {
    int i = blockIdx.x * blockDim.x + threadIdx.x;
    if (i < E) atomicAdd(deg + dst[i], 1);
}

__global__ void k_dinv(const int* __restrict__ deg, float* __restrict__ dinv, int n) {
    int i = blockIdx.x * blockDim.x + threadIdx.x;
    if (i < n) dinv[i] = 1.0f / sqrtf((float)deg[i] + 1.0f);
}

// ---- exclusive scan of deg -> rowstart (2-level, 1024 elems/block) ----
__global__ __launch_bounds__(256) void k_scan1(const int* __restrict__ deg,
                                               int* __restrict__ excl,
                                               int* __restrict__ bsum, int n) {
    __shared__ int tmp[256];
    int b = blockIdx.x, t = threadIdx.x;
    int base = b * 1024 + t * 4;
    int v[4];
#pragma unroll
    for (int j = 0; j < 4; ++j) v[j] = (base + j < n) ? deg[base + j] : 0;
    int s = v[0] + v[1] + v[2] + v[3];
    tmp[t] = s;
    __syncthreads();
    for (int off = 1; off < 256; off <<= 1) {
        int x = (t >= off) ? tmp[t - off] : 0;
        __syncthreads();
        tmp[t] += x;
        __syncthreads();
    }
    int run = tmp[t] - s;  // exclusive prefix within block
#pragma unroll
    for (int j = 0; j < 4; ++j) {
        if (base + j < n) excl[base + j] = run;
        run += v[j];
    }
    if (t == 255) bsum[b] = tmp[255];
}

__global__ void k_scan2(int* __restrict__ bsum, int nb) {
    if (threadIdx.x == 0) {
        int run = 0;
        for (int i = 0; i < nb; ++i) { int v = bsum[i]; bsum[i] = run; run += v; }
    }
}

__global__ void k_scan3(const int* __restrict__ excl, const int* __restrict__ bsum,
                        int* __restrict__ rowstart, int n, int E) {
    int i = blockIdx.x * blockDim.x + threadIdx.x;
    if (i < n) rowstart[i] = excl[i] + bsum[i >> 10];
    if (i == 0) rowstart[n] = E;
}

// ---- CSR fill: col[p]=src, nrm[p]=dinv[s]*dinv[d] ----
__global__ void k_fill(const int* __restrict__ src, const int* __restrict__ dst,
                       const float* __restrict__ dinv, const int* __restrict__ rowstart,
                       int* __restrict__ cnt, int* __restrict__ col,
                       float* __restrict__ nrm, int E) {
    int e = blockIdx.x * blockDim.x + threadIdx.x;
    if (e >= E) return;
    int s = src[e], d = dst[e];
    int p = rowstart[d] + atomicAdd(cnt + d, 1);
    col[p] = s;
    nrm[p] = dinv[s] * dinv[d];
}

// ---- GEMM: out[n,64] = (relu?)(A[n,K]) @ W[K,64]; one row per wave ----
template<int K, bool RELU>
__global__ __launch_bounds__(256) void k_gemm(const float* __restrict__ A,
                                              const float* __restrict__ W,
                                              float* __restrict__ out, int n) {
    __shared__ float Ws[K * HID];
    for (int i = threadIdx.x; i < K * HID; i += 256) Ws[i] = W[i];
    __syncthreads();
    const int wave = threadIdx.x >> 6, lane = threadIdx.x & 63;
    for (int row = blockIdx.x * 4 + wave; row < n; row += gridDim.x * 4) {
        const float* a = A + (size_t)row * K;
        float acc = 0.f;
#pragma unroll
        for (int k4 = 0; k4 < K / 4; ++k4) {
            float4 v = *(const float4*)(a + k4 * 4);
            if (RELU) {
                v.x = fmaxf(v.x, 0.f); v.y = fmaxf(v.y, 0.f);
                v.z = fmaxf(v.z, 0.f); v.w = fmaxf(v.w, 0.f);
            }
            acc = fmaf(v.x, Ws[(k4 * 4 + 0) * HID + lane], acc);
            acc = fmaf(v.y, Ws[(k4 * 4 + 1) * HID + lane], acc);
            acc = fmaf(v.z, Ws[(k4 * 4 + 2) * HID + lane], acc);
            acc = fmaf(v.w, Ws[(k4 * 4 + 3) * HID + lane], acc);
        }
        out[(size_t)row * HID + lane] = acc;
    }
}

// ---- CSR gather: out[i,:] = b + h[i,:]*dinv[i]^2 + sum_j h[col[j],:]*nrm[j] ----
__global__ __launch_bounds__(256) void k_gather(const float* __restrict__ h,
                                                const int* __restrict__ rowstart,
                                                const int* __restrict__ col,
                                                const float* __restrict__ nrm,
                                                const float* __restrict__ dinv,
                                                const float* __restrict__ bias,
                                                float* __restrict__ out, int n) {
    const int wave = threadIdx.x >> 6, lane = threadIdx.x & 63;
    const int node = blockIdx.x * 4 + wave;
    if (node >= n) return;
    float di = dinv[node];
    float acc = fmaf(h[(size_t)node * HID + lane], di * di, bias[lane]);
    float acc2 = 0.f;
    int j = rowstart[node], end = rowstart[node + 1];
    for (; j + 1 < end; j += 2) {
        int c0 = col[j], c1 = col[j + 1];
        float w0 = nrm[j], w1 = nrm[j + 1];
        acc  = fmaf(h[(size_t)c0 * HID + lane], w0, acc);
        acc2 = fmaf(h[(size_t)c1 * HID + lane], w1, acc2);
    }
    if (j < end) acc = fmaf(h[(size_t)col[j] * HID + lane], nrm[j], acc);
    out[(size_t)node * HID + lane] = acc + acc2;
}

// ---- mean pool per graph (batch sorted): block per graph, binary search ----
__global__ __launch_bounds__(256) void k_pool(const float* __restrict__ h,
                                              const int* __restrict__ batch,
                                              float* __restrict__ gm, int n) {
    int g = blockIdx.x;
    int lo = 0, hi = n;
    while (lo < hi) { int m = (lo + hi) >> 1; if (batch[m] < g) lo = m + 1; else hi = m; }
    int lo2 = lo, hi2 = n;
    while (lo2 < hi2) { int m = (lo2 + hi2) >> 1; if (batch[m] < g + 1) lo2 = m + 1; else hi2 = m; }
    int col = threadIdx.x & 63, seg = threadIdx.x >> 6;
    float acc = 0.f;
    for (int r = lo + seg; r < lo2; r += 4)
        acc += fmaxf(h[(size_t)r * HID + col], 0.f);
    __shared__ float red[4][HID];
    red[seg][col] = acc;
    __syncthreads();
    if (seg == 0) {
        float ssum = red[0][col] + red[1][col] + red[2][col] + red[3][col];
        float cnt = (float)(lo2 - lo);
        gm[g * HID + col] = ssum / fmaxf(cnt, 1.0f);
    }
}

// ---- MLP head ----
__global__ void k_head(const float* __restrict__ gm, const float* __restrict__ Wc1,
                       const float* __restrict__ bc1, const float* __restrict__ Wc2,
                       const float* __restrict__ bc2, float* __restrict__ outp) {
    int g = threadIdx.x;
    if (g >= NG) return;
    float o = bc2[0];
    for (int j = 0; j < 32; ++j) {
        float z = bc1[j];
        for (int k = 0; k < HID; ++k) z = fmaf(gm[g * HID + k], Wc1[k * 32 + j], z);
        o = fmaf(fmaxf(z, 0.f), Wc2[j], o);
    }
    outp[g] = o;
}

extern "C" void kernel_launch(void* const* d_in, const int* in_sizes, int n_in,
                              void* d_out, int out_size, void* d_ws, size_t ws_size,
                              hipStream_t stream) {
    const float* x    = (const float*)d_in[0];
    const int*   ei   = (const int*)d_in[1];
    const int*   batch= (const int*)d_in[2];
    const float* W1   = (const float*)d_in[3];
    const float* b1   = (const float*)d_in[4];
    const float* W2   = (const float*)d_in[5];
    const float* b2   = (const float*)d_in[6];
    const float* Wc1  = (const float*)d_in[7];
    const float* bc1  = (const float*)d_in[8];
    const float* Wc2  = (const float*)d_in[9];
    const float* bc2  = (const float*)d_in[10];

    const int E = in_sizes[1] / 2;
    const int n = in_sizes[0] / 128;   // 50000 nodes
    const int* srcp = ei;
    const int* dstp = ei + E;
    const int nb = (n + 1023) / 1024;

    char* ws = (char*)d_ws;
    auto alloc = [&](size_t bytes) {
        char* p = ws;
        ws += (bytes + 255) & ~(size_t)255;
        return p;
    };
    int*   deg      = (int*)  alloc((size_t)n * 4);
    float* dinv     = (float*)alloc((size_t)n * 4);
    int*   excl     = (int*)  alloc((size_t)n * 4);
    int*   bsum     = (int*)  alloc((size_t)nb * 4);
    int*   rowstart = (int*)  alloc((size_t)(n + 1) * 4);
    int*   cnt      = (int*)  alloc((size_t)n * 4);
    int*   col      = (int*)  alloc((size_t)E * 4);
    float* nrm      = (float*)alloc((size_t)E * 4);
    float* bufA     = (float*)alloc((size_t)n * HID * 4);
    float* bufB     = (float*)alloc((size_t)n * HID * 4);
    float* gm       = (float*)alloc((size_t)NG * HID * 4);

    hipMemsetAsync(deg, 0, (size_t)n * 4, stream);
    hipMemsetAsync(cnt, 0, (size_t)n * 4, stream);

    // CSR build (shared by both layers)
    k_deg  <<<(E + 255) / 256, 256, 0, stream>>>(dstp, E, deg);
    k_dinv <<<(n + 255) / 256, 256, 0, stream>>>(deg, dinv, n);
    k_scan1<<<nb, 256, 0, stream>>>(deg, excl, bsum, n);
    k_scan2<<<1, 64, 0, stream>>>(bsum, nb);
    k_scan3<<<(n + 255) / 256, 256, 0, stream>>>(excl, bsum, rowstart, n, E);
    k_fill <<<(E + 255) / 256, 256, 0, stream>>>(srcp, dstp, dinv, rowstart, cnt, col, nrm, E);

    // Layer 1
    k_gemm<128, false><<<1024, 256, 0, stream>>>(x, W1, bufA, n);
    k_gather<<<(n + 3) / 4, 256, 0, stream>>>(bufA, rowstart, col, nrm, dinv, b1, bufB, n);

    // Layer 2 (relu of layer-1 output fused into the GEMM's A-load)
    k_gemm<64, true><<<1024, 256, 0, stream>>>(bufB, W2, bufA, n);
    k_gather<<<(n + 3) / 4, 256, 0, stream>>>(bufA, rowstart, col, nrm, dinv, b2, bufB, n);

    // Pool (relu fused) + head
    k_pool<<<NG, 256, 0, stream>>>(bufB, batch, gm, n);
    k_head<<<1, 64, 0, stream>>>(gm, Wc1, bc1, Wc2, bc2, (float*)d_out);
}

// Round 3
// 310.872 us; speedup vs baseline: 5.1415x; 1.2447x over previous
//
#include <hip/hip_runtime.h>
#include <math.h>

#define NG 64
#define HID 64

// ---- degree count (in-degree from edges; self-loop added in dinv) ----
__global__ void k_deg(const int* __restrict__ dst, int E, int* __restrict__ deg) {
    int i = blockIdx.x * blockDim.x + threadIdx.x;
    if (i < E) atomicAdd(deg + dst[i], 1);
}

__global__ void k_dinv(const int* __restrict__ deg, float* __restrict__ dinv, int n) {
    int i = blockIdx.x * blockDim.x + threadIdx.x;
    if (i < n) dinv[i] = 1.0f / sqrtf((float)deg[i] + 1.0f);
}

// ---- exclusive scan of deg -> rowstart (2-level, 1024 elems/block) ----
__global__ __launch_bounds__(256) void k_scan1(const int* __restrict__ deg,
                                               int* __restrict__ excl,
                                               int* __restrict__ bsum, int n) {
    __shared__ int tmp[256];
    int b = blockIdx.x, t = threadIdx.x;
    int base = b * 1024 + t * 4;
    int v[4];
#pragma unroll
    for (int j = 0; j < 4; ++j) v[j] = (base + j < n) ? deg[base + j] : 0;
    int s = v[0] + v[1] + v[2] + v[3];
    tmp[t] = s;
    __syncthreads();
    for (int off = 1; off < 256; off <<= 1) {
        int x = (t >= off) ? tmp[t - off] : 0;
        __syncthreads();
        tmp[t] += x;
        __syncthreads();
    }
    int run = tmp[t] - s;  // exclusive prefix within block
#pragma unroll
    for (int j = 0; j < 4; ++j) {
        if (base + j < n) excl[base + j] = run;
        run += v[j];
    }
    if (t == 255) bsum[b] = tmp[255];
}

__global__ void k_scan2(int* __restrict__ bsum, int nb) {
    if (threadIdx.x == 0) {
        int run = 0;
        for (int i = 0; i < nb; ++i) { int v = bsum[i]; bsum[i] = run; run += v; }
    }
}

__global__ void k_scan3(const int* __restrict__ excl, const int* __restrict__ bsum,
                        int* __restrict__ rowstart, int n, int E) {
    int i = blockIdx.x * blockDim.x + threadIdx.x;
    if (i < n) rowstart[i] = excl[i] + bsum[i >> 10];
    if (i == 0) rowstart[n] = E;
}

// ---- CSR fill: col[p]=src, nrm[p]=dinv[s]*dinv[d] ----
__global__ void k_fill(const int* __restrict__ src, const int* __restrict__ dst,
                       const float* __restrict__ dinv, const int* __restrict__ rowstart,
                       int* __restrict__ cnt, int* __restrict__ col,
                       float* __restrict__ nrm, int E) {
    int e = blockIdx.x * blockDim.x + threadIdx.x;
    if (e >= E) return;
    int s = src[e], d = dst[e];
    int p = rowstart[d] + atomicAdd(cnt + d, 1);
    col[p] = s;
    nrm[p] = dinv[s] * dinv[d];
}

// ---- GEMM: out[n,64] = (relu?)(A[n,K]) @ W[K,64]
// 8 rows per wave: A rows staged in LDS, read back as broadcast b128;
// W read once per 4-k per wave (b32, 2-way aliasing = free).
template<int K, bool RELU>
__global__ __launch_bounds__(256) void k_gemm(const float* __restrict__ A,
                                              const float* __restrict__ W,
                                              float* __restrict__ out, int n) {
    __shared__ float Ws[K * HID];
    __shared__ float As[4][8][K];
    for (int i = threadIdx.x; i < K * HID; i += 256) Ws[i] = W[i];
    __syncthreads();
    const int wave = threadIdx.x >> 6, lane = threadIdx.x & 63;
    const int tile = blockIdx.x * 4 + wave;
    const int row0 = tile * 8;
    if (row0 >= n) return;

    // stage 8 rows: lane handles row (lane>>3), chunk of K/8 floats
    {
        const int r = lane >> 3;
        const int c = (lane & 7) * (K / 8);
        const int row = row0 + r;
#pragma unroll
        for (int j = 0; j < K / 32; ++j) {
            float4 v;
            if (row < n) v = *(const float4*)(A + (size_t)row * K + c + j * 4);
            else v = make_float4(0.f, 0.f, 0.f, 0.f);
            if (RELU) {
                v.x = fmaxf(v.x, 0.f); v.y = fmaxf(v.y, 0.f);
                v.z = fmaxf(v.z, 0.f); v.w = fmaxf(v.w, 0.f);
            }
            *(float4*)&As[wave][r][c + j * 4] = v;
        }
    }
    // same-wave LDS write->read: compiler inserts lgkmcnt waits; no barrier needed

    float acc[8] = {0.f, 0.f, 0.f, 0.f, 0.f, 0.f, 0.f, 0.f};
#pragma unroll 8
    for (int k4 = 0; k4 < K / 4; ++k4) {
        const float w0 = Ws[(k4 * 4 + 0) * HID + lane];
        const float w1 = Ws[(k4 * 4 + 1) * HID + lane];
        const float w2 = Ws[(k4 * 4 + 2) * HID + lane];
        const float w3 = Ws[(k4 * 4 + 3) * HID + lane];
#pragma unroll
        for (int r = 0; r < 8; ++r) {
            float4 av = *(const float4*)&As[wave][r][k4 * 4];
            float t0 = fmaf(av.x, w0, acc[r]);
            float t1 = fmaf(av.y, w1, t0);
            float t2 = fmaf(av.z, w2, t1);
            acc[r] = fmaf(av.w, w3, t2);
        }
    }
#pragma unroll
    for (int r = 0; r < 8; ++r) {
        int row = row0 + r;
        if (row < n) out[(size_t)row * HID + lane] = acc[r];
    }
}

// ---- CSR gather: out[i,:] = b + h[i,:]*dinv[i]^2 + sum_j h[col[j],:]*nrm[j] ----
__global__ __launch_bounds__(256) void k_gather(const float* __restrict__ h,
                                                const int* __restrict__ rowstart,
                                                const int* __restrict__ col,
                                                const float* __restrict__ nrm,
                                                const float* __restrict__ dinv,
                                                const float* __restrict__ bias,
                                                float* __restrict__ out, int n) {
    const int wave = threadIdx.x >> 6, lane = threadIdx.x & 63;
    const int node = blockIdx.x * 4 + wave;
    if (node >= n) return;
    float di = dinv[node];
    float acc = fmaf(h[(size_t)node * HID + lane], di * di, bias[lane]);
    float acc2 = 0.f;
    int j = rowstart[node], end = rowstart[node + 1];
    for (; j + 1 < end; j += 2) {
        int c0 = col[j], c1 = col[j + 1];
        float w0 = nrm[j], w1 = nrm[j + 1];
        acc  = fmaf(h[(size_t)c0 * HID + lane], w0, acc);
        acc2 = fmaf(h[(size_t)c1 * HID + lane], w1, acc2);
    }
    if (j < end) acc = fmaf(h[(size_t)col[j] * HID + lane], nrm[j], acc);
    out[(size_t)node * HID + lane] = acc + acc2;
}

// ---- mean pool per graph (batch sorted): block per graph, float4 lanes ----
__global__ __launch_bounds__(256) void k_pool(const float* __restrict__ h,
                                              const int* __restrict__ batch,
                                              float* __restrict__ gm, int n) {
    int g = blockIdx.x;
    int lo = 0, hi = n;
    while (lo < hi) { int m = (lo + hi) >> 1; if (batch[m] < g) lo = m + 1; else hi = m; }
    int lo2 = lo, hi2 = n;
    while (lo2 < hi2) { int m = (lo2 + hi2) >> 1; if (batch[m] < g + 1) lo2 = m + 1; else hi2 = m; }
    const int t = threadIdx.x;
    const int rg = t >> 4;          // 16 row slots
    const int c4 = (t & 15) * 4;    // 16 col chunks of 4
    float4 acc = make_float4(0.f, 0.f, 0.f, 0.f);
    for (int r = lo + rg; r < lo2; r += 16) {
        float4 v = *(const float4*)(h + (size_t)r * HID + c4);
        acc.x += fmaxf(v.x, 0.f); acc.y += fmaxf(v.y, 0.f);
        acc.z += fmaxf(v.z, 0.f); acc.w += fmaxf(v.w, 0.f);
    }
    __shared__ float4 red[16][16];
    red[rg][t & 15] = acc;
    __syncthreads();
    if (t < 16) {
        float4 s = red[0][t];
#pragma unroll
        for (int g2 = 1; g2 < 16; ++g2) {
            float4 v = red[g2][t];
            s.x += v.x; s.y += v.y; s.z += v.z; s.w += v.w;
        }
        float cnt = fmaxf((float)(lo2 - lo), 1.0f);
        float inv = 1.0f / cnt;
        float* o = gm + g * HID + t * 4;
        o[0] = s.x * inv; o[1] = s.y * inv; o[2] = s.z * inv; o[3] = s.w * inv;
    }
}

// ---- MLP head ----
__global__ void k_head(const float* __restrict__ gm, const float* __restrict__ Wc1,
                       const float* __restrict__ bc1, const float* __restrict__ Wc2,
                       const float* __restrict__ bc2, float* __restrict__ outp) {
    int g = threadIdx.x;
    if (g >= NG) return;
    float o = bc2[0];
    for (int j = 0; j < 32; ++j) {
        float z = bc1[j];
        for (int k = 0; k < HID; ++k) z = fmaf(gm[g * HID + k], Wc1[k * 32 + j], z);
        o = fmaf(fmaxf(z, 0.f), Wc2[j], o);
    }
    outp[g] = o;
}

extern "C" void kernel_launch(void* const* d_in, const int* in_sizes, int n_in,
                              void* d_out, int out_size, void* d_ws, size_t ws_size,
                              hipStream_t stream) {
    const float* x    = (const float*)d_in[0];
    const int*   ei   = (const int*)d_in[1];
    const int*   batch= (const int*)d_in[2];
    const float* W1   = (const float*)d_in[3];
    const float* b1   = (const float*)d_in[4];
    const float* W2   = (const float*)d_in[5];
    const float* b2   = (const float*)d_in[6];
    const float* Wc1  = (const float*)d_in[7];
    const float* bc1  = (const float*)d_in[8];
    const float* Wc2  = (const float*)d_in[9];
    const float* bc2  = (const float*)d_in[10];

    const int E = in_sizes[1] / 2;
    const int n = in_sizes[0] / 128;   // 50000 nodes
    const int* srcp = ei;
    const int* dstp = ei + E;
    const int nb = (n + 1023) / 1024;

    char* ws = (char*)d_ws;
    auto alloc = [&](size_t bytes) {
        char* p = ws;
        ws += (bytes + 255) & ~(size_t)255;
        return p;
    };
    int*   deg      = (int*)  alloc((size_t)n * 4);
    float* dinv     = (float*)alloc((size_t)n * 4);
    int*   excl     = (int*)  alloc((size_t)n * 4);
    int*   bsum     = (int*)  alloc((size_t)nb * 4);
    int*   rowstart = (int*)  alloc((size_t)(n + 1) * 4);
    int*   cnt      = (int*)  alloc((size_t)n * 4);
    int*   col      = (int*)  alloc((size_t)E * 4);
    float* nrm      = (float*)alloc((size_t)E * 4);
    float* bufA     = (float*)alloc((size_t)n * HID * 4);
    float* bufB     = (float*)alloc((size_t)n * HID * 4);
    float* gm       = (float*)alloc((size_t)NG * HID * 4);

    hipMemsetAsync(deg, 0, (size_t)n * 4, stream);
    hipMemsetAsync(cnt, 0, (size_t)n * 4, stream);

    // CSR build (shared by both layers)
    k_deg  <<<(E + 255) / 256, 256, 0, stream>>>(dstp, E, deg);
    k_dinv <<<(n + 255) / 256, 256, 0, stream>>>(deg, dinv, n);
    k_scan1<<<nb, 256, 0, stream>>>(deg, excl, bsum, n);
    k_scan2<<<1, 64, 0, stream>>>(bsum, nb);
    k_scan3<<<(n + 255) / 256, 256, 0, stream>>>(excl, bsum, rowstart, n, E);
    k_fill <<<(E + 255) / 256, 256, 0, stream>>>(srcp, dstp, dinv, rowstart, cnt, col, nrm, E);

    const int tiles = (n + 7) / 8;
    const int gblocks = (tiles + 3) / 4;

    // Layer 1
    k_gemm<128, false><<<gblocks, 256, 0, stream>>>(x, W1, bufA, n);
    k_gather<<<(n + 3) / 4, 256, 0, stream>>>(bufA, rowstart, col, nrm, dinv, b1, bufB, n);

    // Layer 2 (relu of layer-1 output fused into the GEMM's A-staging)
    k_gemm<64, true><<<gblocks, 256, 0, stream>>>(bufB, W2, bufA, n);
    k_gather<<<(n + 3) / 4, 256, 0, stream>>>(bufA, rowstart, col, nrm, dinv, b2, bufB, n);

    // Pool (relu fused) + head
    k_pool<<<NG, 256, 0, stream>>>(bufB, batch, gm, n);
    k_head<<<1, 64, 0, stream>>>(gm, Wc1, bc1, Wc2, bc2, (float*)d_out);
}

// Round 4
// 275.851 us; speedup vs baseline: 5.7943x; 1.1270x over previous
//
#include <hip/hip_runtime.h>
#include <math.h>

#define NG 64
#define HID 64

// ---- degree count (in-degree from edges; self-loop added in dinv) ----
__global__ void k_deg(const int* __restrict__ dst, int E, int* __restrict__ deg) {
    int i = blockIdx.x * blockDim.x + threadIdx.x;
    if (i < E) atomicAdd(deg + dst[i], 1);
}

__global__ void k_dinv(const int* __restrict__ deg, float* __restrict__ dinv, int n) {
    int i = blockIdx.x * blockDim.x + threadIdx.x;
    if (i < n) dinv[i] = 1.0f / sqrtf((float)deg[i] + 1.0f);
}

// ---- exclusive scan of deg -> rowstart (2-level, 1024 elems/block) ----
__global__ __launch_bounds__(256) void k_scan1(const int* __restrict__ deg,
                                               int* __restrict__ excl,
                                               int* __restrict__ bsum, int n) {
    __shared__ int tmp[256];
    int b = blockIdx.x, t = threadIdx.x;
    int base = b * 1024 + t * 4;
    int v[4];
#pragma unroll
    for (int j = 0; j < 4; ++j) v[j] = (base + j < n) ? deg[base + j] : 0;
    int s = v[0] + v[1] + v[2] + v[3];
    tmp[t] = s;
    __syncthreads();
    for (int off = 1; off < 256; off <<= 1) {
        int x = (t >= off) ? tmp[t - off] : 0;
        __syncthreads();
        tmp[t] += x;
        __syncthreads();
    }
    int run = tmp[t] - s;  // exclusive prefix within block
#pragma unroll
    for (int j = 0; j < 4; ++j) {
        if (base + j < n) excl[base + j] = run;
        run += v[j];
    }
    if (t == 255) bsum[b] = tmp[255];
}

__global__ void k_scan2(int* __restrict__ bsum, int nb) {
    if (threadIdx.x == 0) {
        int run = 0;
        for (int i = 0; i < nb; ++i) { int v = bsum[i]; bsum[i] = run; run += v; }
    }
}

__global__ void k_scan3(const int* __restrict__ excl, const int* __restrict__ bsum,
                        int* __restrict__ rowstart, int n, int E) {
    int i = blockIdx.x * blockDim.x + threadIdx.x;
    if (i < n) rowstart[i] = excl[i] + bsum[i >> 10];
    if (i == 0) rowstart[n] = E;
}

// ---- CSR fill: cn[p] = (src, dinv[s]*dinv[d]) packed, single 8B store ----
__global__ void k_fill(const int* __restrict__ src, const int* __restrict__ dst,
                       const float* __restrict__ dinv, const int* __restrict__ rowstart,
                       int* __restrict__ cnt, int2* __restrict__ cn, int E) {
    int e = blockIdx.x * blockDim.x + threadIdx.x;
    if (e >= E) return;
    int s = src[e], d = dst[e];
    int p = rowstart[d] + atomicAdd(cnt + d, 1);
    cn[p] = make_int2(s, __float_as_int(dinv[s] * dinv[d]));
}

// ---- GEMM: out[n,64] = (relu?)(A[n,K]) @ W[K,64]
// 8 rows per wave: A rows staged in LDS, read back as broadcast b128;
// W read once per 4-k per wave (b32, 2-way aliasing = free).
template<int K, bool RELU>
__global__ __launch_bounds__(256) void k_gemm(const float* __restrict__ A,
                                              const float* __restrict__ W,
                                              float* __restrict__ out, int n) {
    __shared__ float Ws[K * HID];
    __shared__ float As[4][8][K];
    for (int i = threadIdx.x; i < K * HID; i += 256) Ws[i] = W[i];
    __syncthreads();
    const int wave = threadIdx.x >> 6, lane = threadIdx.x & 63;
    const int tile = blockIdx.x * 4 + wave;
    const int row0 = tile * 8;
    if (row0 >= n) return;

    // stage 8 rows: lane handles row (lane>>3), chunk of K/8 floats
    {
        const int r = lane >> 3;
        const int c = (lane & 7) * (K / 8);
        const int row = row0 + r;
#pragma unroll
        for (int j = 0; j < K / 32; ++j) {
            float4 v;
            if (row < n) v = *(const float4*)(A + (size_t)row * K + c + j * 4);
            else v = make_float4(0.f, 0.f, 0.f, 0.f);
            if (RELU) {
                v.x = fmaxf(v.x, 0.f); v.y = fmaxf(v.y, 0.f);
                v.z = fmaxf(v.z, 0.f); v.w = fmaxf(v.w, 0.f);
            }
            *(float4*)&As[wave][r][c + j * 4] = v;
        }
    }
    // same-wave LDS write->read: compiler inserts lgkmcnt waits; no barrier needed

    float acc[8] = {0.f, 0.f, 0.f, 0.f, 0.f, 0.f, 0.f, 0.f};
#pragma unroll 8
    for (int k4 = 0; k4 < K / 4; ++k4) {
        const float w0 = Ws[(k4 * 4 + 0) * HID + lane];
        const float w1 = Ws[(k4 * 4 + 1) * HID + lane];
        const float w2 = Ws[(k4 * 4 + 2) * HID + lane];
        const float w3 = Ws[(k4 * 4 + 3) * HID + lane];
#pragma unroll
        for (int r = 0; r < 8; ++r) {
            float4 av = *(const float4*)&As[wave][r][k4 * 4];
            float t0 = fmaf(av.x, w0, acc[r]);
            float t1 = fmaf(av.y, w1, t0);
            float t2 = fmaf(av.z, w2, t1);
            acc[r] = fmaf(av.w, w3, t2);
        }
    }
#pragma unroll
    for (int r = 0; r < 8; ++r) {
        int row = row0 + r;
        if (row < n) out[(size_t)row * HID + lane] = acc[r];
    }
}

// ---- CSR gather, 8-deep software pipeline:
// out[i,:] = b + h[i,:]*dinv[i]^2 + sum_j h[cn[j].x,:]*cn[j].w ----
__global__ __launch_bounds__(256) void k_gather(const float* __restrict__ h,
                                                const int* __restrict__ rowstart,
                                                const int2* __restrict__ cn,
                                                const float* __restrict__ dinv,
                                                const float* __restrict__ bias,
                                                float* __restrict__ out, int n) {
    const int wave = threadIdx.x >> 6, lane = threadIdx.x & 63;
    const int node = blockIdx.x * 4 + wave;
    if (node >= n) return;
    float di = dinv[node];
    float acc = fmaf(h[(size_t)node * HID + lane], di * di, bias[lane]);
    float acc2 = 0.f;
    int j = rowstart[node], end = rowstart[node + 1];

    // full chunks of 8: 8 metadata loads, then 8 independent row loads in flight
    while (end - j >= 8) {
        int2 cw[8];
#pragma unroll
        for (int t = 0; t < 8; ++t) cw[t] = cn[j + t];
        float v[8];
#pragma unroll
        for (int t = 0; t < 8; ++t) v[t] = h[(size_t)cw[t].x * HID + lane];
#pragma unroll
        for (int t = 0; t < 8; ++t) {
            float w = __int_as_float(cw[t].y);
            if (t & 1) acc2 = fmaf(v[t], w, acc2);
            else       acc  = fmaf(v[t], w, acc);
        }
        j += 8;
    }
    // tail (<8)
    for (; j + 1 < end; j += 2) {
        int2 c0 = cn[j], c1 = cn[j + 1];
        acc  = fmaf(h[(size_t)c0.x * HID + lane], __int_as_float(c0.y), acc);
        acc2 = fmaf(h[(size_t)c1.x * HID + lane], __int_as_float(c1.y), acc2);
    }
    if (j < end) {
        int2 c0 = cn[j];
        acc = fmaf(h[(size_t)c0.x * HID + lane], __int_as_float(c0.y), acc);
    }
    out[(size_t)node * HID + lane] = acc + acc2;
}

// ---- mean pool per graph (batch sorted): block per graph, float4 lanes ----
__global__ __launch_bounds__(256) void k_pool(const float* __restrict__ h,
                                              const int* __restrict__ batch,
                                              float* __restrict__ gm, int n) {
    int g = blockIdx.x;
    int lo = 0, hi = n;
    while (lo < hi) { int m = (lo + hi) >> 1; if (batch[m] < g) lo = m + 1; else hi = m; }
    int lo2 = lo, hi2 = n;
    while (lo2 < hi2) { int m = (lo2 + hi2) >> 1; if (batch[m] < g + 1) lo2 = m + 1; else hi2 = m; }
    const int t = threadIdx.x;
    const int rg = t >> 4;          // 16 row slots
    const int c4 = (t & 15) * 4;    // 16 col chunks of 4
    float4 acc = make_float4(0.f, 0.f, 0.f, 0.f);
    for (int r = lo + rg; r < lo2; r += 16) {
        float4 v = *(const float4*)(h + (size_t)r * HID + c4);
        acc.x += fmaxf(v.x, 0.f); acc.y += fmaxf(v.y, 0.f);
        acc.z += fmaxf(v.z, 0.f); acc.w += fmaxf(v.w, 0.f);
    }
    __shared__ float4 red[16][16];
    red[rg][t & 15] = acc;
    __syncthreads();
    if (t < 16) {
        float4 s = red[0][t];
#pragma unroll
        for (int g2 = 1; g2 < 16; ++g2) {
            float4 v = red[g2][t];
            s.x += v.x; s.y += v.y; s.z += v.z; s.w += v.w;
        }
        float cnt = fmaxf((float)(lo2 - lo), 1.0f);
        float inv = 1.0f / cnt;
        float* o = gm + g * HID + t * 4;
        o[0] = s.x * inv; o[1] = s.y * inv; o[2] = s.z * inv; o[3] = s.w * inv;
    }
}

// ---- MLP head ----
__global__ void k_head(const float* __restrict__ gm, const float* __restrict__ Wc1,
                       const float* __restrict__ bc1, const float* __restrict__ Wc2,
                       const float* __restrict__ bc2, float* __restrict__ outp) {
    int g = threadIdx.x;
    if (g >= NG) return;
    float o = bc2[0];
    for (int j = 0; j < 32; ++j) {
        float z = bc1[j];
        for (int k = 0; k < HID; ++k) z = fmaf(gm[g * HID + k], Wc1[k * 32 + j], z);
        o = fmaf(fmaxf(z, 0.f), Wc2[j], o);
    }
    outp[g] = o;
}

extern "C" void kernel_launch(void* const* d_in, const int* in_sizes, int n_in,
                              void* d_out, int out_size, void* d_ws, size_t ws_size,
                              hipStream_t stream) {
    const float* x    = (const float*)d_in[0];
    const int*   ei   = (const int*)d_in[1];
    const int*   batch= (const int*)d_in[2];
    const float* W1   = (const float*)d_in[3];
    const float* b1   = (const float*)d_in[4];
    const float* W2   = (const float*)d_in[5];
    const float* b2   = (const float*)d_in[6];
    const float* Wc1  = (const float*)d_in[7];
    const float* bc1  = (const float*)d_in[8];
    const float* Wc2  = (const float*)d_in[9];
    const float* bc2  = (const float*)d_in[10];

    const int E = in_sizes[1] / 2;
    const int n = in_sizes[0] / 128;   // 50000 nodes
    const int* srcp = ei;
    const int* dstp = ei + E;
    const int nb = (n + 1023) / 1024;

    char* ws = (char*)d_ws;
    auto alloc = [&](size_t bytes) {
        char* p = ws;
        ws += (bytes + 255) & ~(size_t)255;
        return p;
    };
    int*   deg      = (int*)  alloc((size_t)n * 4);
    float* dinv     = (float*)alloc((size_t)n * 4);
    int*   excl     = (int*)  alloc((size_t)n * 4);
    int*   bsum     = (int*)  alloc((size_t)nb * 4);
    int*   rowstart = (int*)  alloc((size_t)(n + 1) * 4);
    int*   cnt      = (int*)  alloc((size_t)n * 4);
    int2*  cn       = (int2*) alloc((size_t)E * 8);
    float* bufA     = (float*)alloc((size_t)n * HID * 4);
    float* bufB     = (float*)alloc((size_t)n * HID * 4);
    float* gm       = (float*)alloc((size_t)NG * HID * 4);

    hipMemsetAsync(deg, 0, (size_t)n * 4, stream);
    hipMemsetAsync(cnt, 0, (size_t)n * 4, stream);

    // CSR build (shared by both layers)
    k_deg  <<<(E + 255) / 256, 256, 0, stream>>>(dstp, E, deg);
    k_dinv <<<(n + 255) / 256, 256, 0, stream>>>(deg, dinv, n);
    k_scan1<<<nb, 256, 0, stream>>>(deg, excl, bsum, n);
    k_scan2<<<1, 64, 0, stream>>>(bsum, nb);
    k_scan3<<<(n + 255) / 256, 256, 0, stream>>>(excl, bsum, rowstart, n, E);
    k_fill <<<(E + 255) / 256, 256, 0, stream>>>(srcp, dstp, dinv, rowstart, cnt, cn, E);

    const int tiles = (n + 7) / 8;
    const int gblocks = (tiles + 3) / 4;

    // Layer 1
    k_gemm<128, false><<<gblocks, 256, 0, stream>>>(x, W1, bufA, n);
    k_gather<<<(n + 3) / 4, 256, 0, stream>>>(bufA, rowstart, cn, dinv, b1, bufB, n);

    // Layer 2 (relu of layer-1 output fused into the GEMM's A-staging)
    k_gemm<64, true><<<gblocks, 256, 0, stream>>>(bufB, W2, bufA, n);
    k_gather<<<(n + 3) / 4, 256, 0, stream>>>(bufA, rowstart, cn, dinv, b2, bufB, n);

    // Pool (relu fused) + head
    k_pool<<<NG, 256, 0, stream>>>(bufB, batch, gm, n);
    k_head<<<1, 64, 0, stream>>>(gm, Wc1, bc1, Wc2, bc2, (float*)d_out);
}

// Round 5
// 249.482 us; speedup vs baseline: 6.4067x; 1.1057x over previous
//
#include <hip/hip_runtime.h>
#include <math.h>

#define NG 64
#define HID 64

// ---- degree count + slot rank (in-degree from edges; self-loop in dinv) ----
__global__ void k_deg(const int* __restrict__ dst, int E,
                      int* __restrict__ deg, int* __restrict__ rank) {
    int i = blockIdx.x * blockDim.x + threadIdx.x;
    if (i < E) rank[i] = atomicAdd(deg + dst[i], 1);
}

__global__ void k_dinv(const int* __restrict__ deg, float* __restrict__ dinv, int n) {
    int i = blockIdx.x * blockDim.x + threadIdx.x;
    if (i < n) dinv[i] = 1.0f / sqrtf((float)deg[i] + 1.0f);
}

// ---- exclusive scan of deg -> rowstart (2-level, 1024 elems/block) ----
__global__ __launch_bounds__(256) void k_scan1(const int* __restrict__ deg,
                                               int* __restrict__ excl,
                                               int* __restrict__ bsum, int n) {
    __shared__ int tmp[256];
    int b = blockIdx.x, t = threadIdx.x;
    int base = b * 1024 + t * 4;
    int v[4];
#pragma unroll
    for (int j = 0; j < 4; ++j) v[j] = (base + j < n) ? deg[base + j] : 0;
    int s = v[0] + v[1] + v[2] + v[3];
    tmp[t] = s;
    __syncthreads();
    for (int off = 1; off < 256; off <<= 1) {
        int x = (t >= off) ? tmp[t - off] : 0;
        __syncthreads();
        tmp[t] += x;
        __syncthreads();
    }
    int run = tmp[t] - s;  // exclusive prefix within block
#pragma unroll
    for (int j = 0; j < 4; ++j) {
        if (base + j < n) excl[base + j] = run;
        run += v[j];
    }
    if (t == 255) bsum[b] = tmp[255];
}

__global__ void k_scan2(int* __restrict__ bsum, int nb) {
    if (threadIdx.x == 0) {
        int run = 0;
        for (int i = 0; i < nb; ++i) { int v = bsum[i]; bsum[i] = run; run += v; }
    }
}

__global__ void k_scan3(const int* __restrict__ excl, const int* __restrict__ bsum,
                        int* __restrict__ rowstart, int n, int E) {
    int i = blockIdx.x * blockDim.x + threadIdx.x;
    if (i < n) rowstart[i] = excl[i] + bsum[i >> 10];
    if (i == 0) rowstart[n] = E;
}

// ---- CSR fill (atomic-free): col[rowstart[d]+rank[e]] = src[e] ----
__global__ void k_fill(const int* __restrict__ src, const int* __restrict__ dst,
                       const int* __restrict__ rank, const int* __restrict__ rowstart,
                       int* __restrict__ col, int E) {
    int e = blockIdx.x * blockDim.x + threadIdx.x;
    if (e >= E) return;
    col[rowstart[dst[e]] + rank[e]] = src[e];
}

// ---- GEMM: out[n,64] = ((relu?)(A[n,K]) @ W[K,64]) * dinv[row]
// 8 rows per wave: A rows staged in LDS, read back as broadcast b128;
// W read once per 4-k per wave (b32, 2-way aliasing = free).
template<int K, bool RELU>
__global__ __launch_bounds__(256) void k_gemm(const float* __restrict__ A,
                                              const float* __restrict__ W,
                                              const float* __restrict__ dinv,
                                              float* __restrict__ out, int n) {
    __shared__ float Ws[K * HID];
    __shared__ float As[4][8][K];
    for (int i = threadIdx.x; i < K * HID; i += 256) Ws[i] = W[i];
    __syncthreads();
    const int wave = threadIdx.x >> 6, lane = threadIdx.x & 63;
    const int tile = blockIdx.x * 4 + wave;
    const int row0 = tile * 8;
    if (row0 >= n) return;

    // stage 8 rows: lane handles row (lane>>3), chunk of K/8 floats
    {
        const int r = lane >> 3;
        const int c = (lane & 7) * (K / 8);
        const int row = row0 + r;
#pragma unroll
        for (int j = 0; j < K / 32; ++j) {
            float4 v;
            if (row < n) v = *(const float4*)(A + (size_t)row * K + c + j * 4);
            else v = make_float4(0.f, 0.f, 0.f, 0.f);
            if (RELU) {
                v.x = fmaxf(v.x, 0.f); v.y = fmaxf(v.y, 0.f);
                v.z = fmaxf(v.z, 0.f); v.w = fmaxf(v.w, 0.f);
            }
            *(float4*)&As[wave][r][c + j * 4] = v;
        }
    }
    // same-wave LDS write->read: compiler inserts lgkmcnt waits; no barrier needed

    float acc[8] = {0.f, 0.f, 0.f, 0.f, 0.f, 0.f, 0.f, 0.f};
#pragma unroll 8
    for (int k4 = 0; k4 < K / 4; ++k4) {
        const float w0 = Ws[(k4 * 4 + 0) * HID + lane];
        const float w1 = Ws[(k4 * 4 + 1) * HID + lane];
        const float w2 = Ws[(k4 * 4 + 2) * HID + lane];
        const float w3 = Ws[(k4 * 4 + 3) * HID + lane];
#pragma unroll
        for (int r = 0; r < 8; ++r) {
            float4 av = *(const float4*)&As[wave][r][k4 * 4];
            float t0 = fmaf(av.x, w0, acc[r]);
            float t1 = fmaf(av.y, w1, t0);
            float t2 = fmaf(av.z, w2, t1);
            acc[r] = fmaf(av.w, w3, t2);
        }
    }
#pragma unroll
    for (int r = 0; r < 8; ++r) {
        int row = row0 + r;
        if (row < n) out[(size_t)row * HID + lane] = acc[r] * dinv[row];
    }
}

// ---- CSR gather, 8-deep pipeline, hs pre-scaled by dinv:
// out[i,:] = b + dinv[i] * (hs[i,:] + sum_j hs[col[j],:]) ----
__global__ __launch_bounds__(256) void k_gather(const float* __restrict__ hs,
                                                const int* __restrict__ rowstart,
                                                const int* __restrict__ col,
                                                const float* __restrict__ dinv,
                                                const float* __restrict__ bias,
                                                float* __restrict__ out, int n) {
    const int wave = threadIdx.x >> 6, lane = threadIdx.x & 63;
    const int node = blockIdx.x * 4 + wave;
    if (node >= n) return;
    float di = dinv[node];
    float acc = hs[(size_t)node * HID + lane];
    float acc2 = 0.f;
    int j = rowstart[node], end = rowstart[node + 1];

    // full chunks of 8: 8 metadata loads, then 8 independent row loads in flight
    while (end - j >= 8) {
        int c[8];
#pragma unroll
        for (int t = 0; t < 8; ++t) c[t] = col[j + t];
        float v[8];
#pragma unroll
        for (int t = 0; t < 8; ++t) v[t] = hs[(size_t)c[t] * HID + lane];
#pragma unroll
        for (int t = 0; t < 8; ++t) {
            if (t & 1) acc2 += v[t];
            else       acc  += v[t];
        }
        j += 8;
    }
    // tail (<8)
    for (; j + 1 < end; j += 2) {
        int c0 = col[j], c1 = col[j + 1];
        acc  += hs[(size_t)c0 * HID + lane];
        acc2 += hs[(size_t)c1 * HID + lane];
    }
    if (j < end) acc += hs[(size_t)col[j] * HID + lane];
    out[(size_t)node * HID + lane] = fmaf(acc + acc2, di, bias[lane]);
}

// ---- mean pool per graph (batch sorted): block per graph, float4 lanes ----
__global__ __launch_bounds__(256) void k_pool(const float* __restrict__ h,
                                              const int* __restrict__ batch,
                                              float* __restrict__ gm, int n) {
    int g = blockIdx.x;
    int lo = 0, hi = n;
    while (lo < hi) { int m = (lo + hi) >> 1; if (batch[m] < g) lo = m + 1; else hi = m; }
    int lo2 = lo, hi2 = n;
    while (lo2 < hi2) { int m = (lo2 + hi2) >> 1; if (batch[m] < g + 1) lo2 = m + 1; else hi2 = m; }
    const int t = threadIdx.x;
    const int rg = t >> 4;          // 16 row slots
    const int c4 = (t & 15) * 4;    // 16 col chunks of 4
    float4 acc = make_float4(0.f, 0.f, 0.f, 0.f);
    for (int r = lo + rg; r < lo2; r += 16) {
        float4 v = *(const float4*)(h + (size_t)r * HID + c4);
        acc.x += fmaxf(v.x, 0.f); acc.y += fmaxf(v.y, 0.f);
        acc.z += fmaxf(v.z, 0.f); acc.w += fmaxf(v.w, 0.f);
    }
    __shared__ float4 red[16][16];
    red[rg][t & 15] = acc;
    __syncthreads();
    if (t < 16) {
        float4 s = red[0][t];
#pragma unroll
        for (int g2 = 1; g2 < 16; ++g2) {
            float4 v = red[g2][t];
            s.x += v.x; s.y += v.y; s.z += v.z; s.w += v.w;
        }
        float cnt = fmaxf((float)(lo2 - lo), 1.0f);
        float inv = 1.0f / cnt;
        float* o = gm + g * HID + t * 4;
        o[0] = s.x * inv; o[1] = s.y * inv; o[2] = s.z * inv; o[3] = s.w * inv;
    }
}

// ---- MLP head ----
__global__ void k_head(const float* __restrict__ gm, const float* __restrict__ Wc1,
                       const float* __restrict__ bc1, const float* __restrict__ Wc2,
                       const float* __restrict__ bc2, float* __restrict__ outp) {
    int g = threadIdx.x;
    if (g >= NG) return;
    float o = bc2[0];
    for (int j = 0; j < 32; ++j) {
        float z = bc1[j];
        for (int k = 0; k < HID; ++k) z = fmaf(gm[g * HID + k], Wc1[k * 32 + j], z);
        o = fmaf(fmaxf(z, 0.f), Wc2[j], o);
    }
    outp[g] = o;
}

extern "C" void kernel_launch(void* const* d_in, const int* in_sizes, int n_in,
                              void* d_out, int out_size, void* d_ws, size_t ws_size,
                              hipStream_t stream) {
    const float* x    = (const float*)d_in[0];
    const int*   ei   = (const int*)d_in[1];
    const int*   batch= (const int*)d_in[2];
    const float* W1   = (const float*)d_in[3];
    const float* b1   = (const float*)d_in[4];
    const float* W2   = (const float*)d_in[5];
    const float* b2   = (const float*)d_in[6];
    const float* Wc1  = (const float*)d_in[7];
    const float* bc1  = (const float*)d_in[8];
    const float* Wc2  = (const float*)d_in[9];
    const float* bc2  = (const float*)d_in[10];

    const int E = in_sizes[1] / 2;
    const int n = in_sizes[0] / 128;   // 50000 nodes
    const int* srcp = ei;
    const int* dstp = ei + E;
    const int nb = (n + 1023) / 1024;

    char* ws = (char*)d_ws;
    auto alloc = [&](size_t bytes) {
        char* p = ws;
        ws += (bytes + 255) & ~(size_t)255;
        return p;
    };
    int*   deg      = (int*)  alloc((size_t)n * 4);
    float* dinv     = (float*)alloc((size_t)n * 4);
    int*   excl     = (int*)  alloc((size_t)n * 4);
    int*   bsum     = (int*)  alloc((size_t)nb * 4);
    int*   rowstart = (int*)  alloc((size_t)(n + 1) * 4);
    int*   rank     = (int*)  alloc((size_t)E * 4);
    int*   col      = (int*)  alloc((size_t)E * 4);
    float* bufA     = (float*)alloc((size_t)n * HID * 4);
    float* bufB     = (float*)alloc((size_t)n * HID * 4);
    float* gm       = (float*)alloc((size_t)NG * HID * 4);

    hipMemsetAsync(deg, 0, (size_t)n * 4, stream);

    // CSR build (shared by both layers)
    k_deg  <<<(E + 255) / 256, 256, 0, stream>>>(dstp, E, deg, rank);
    k_dinv <<<(n + 255) / 256, 256, 0, stream>>>(deg, dinv, n);
    k_scan1<<<nb, 256, 0, stream>>>(deg, excl, bsum, n);
    k_scan2<<<1, 64, 0, stream>>>(bsum, nb);
    k_scan3<<<(n + 255) / 256, 256, 0, stream>>>(excl, bsum, rowstart, n, E);
    k_fill <<<(E + 255) / 256, 256, 0, stream>>>(srcp, dstp, rank, rowstart, col, E);

    const int tiles = (n + 7) / 8;
    const int gblocks = (tiles + 3) / 4;

    // Layer 1 (GEMM output pre-scaled by dinv)
    k_gemm<128, false><<<gblocks, 256, 0, stream>>>(x, W1, dinv, bufA, n);
    k_gather<<<(n + 3) / 4, 256, 0, stream>>>(bufA, rowstart, col, dinv, b1, bufB, n);

    // Layer 2 (relu of layer-1 output fused into the GEMM's A-staging)
    k_gemm<64, true><<<gblocks, 256, 0, stream>>>(bufB, W2, dinv, bufA, n);
    k_gather<<<(n + 3) / 4, 256, 0, stream>>>(bufA, rowstart, col, dinv, b2, bufB, n);

    // Pool (relu fused) + head
    k_pool<<<NG, 256, 0, stream>>>(bufB, batch, gm, n);
    k_head<<<1, 64, 0, stream>>>(gm, Wc1, bc1, Wc2, bc2, (float*)d_out);
}

// Round 6
// 237.465 us; speedup vs baseline: 6.7309x; 1.0506x over previous
//
#include <hip/hip_runtime.h>
#include <math.h>

#define NG 64
#define HID 64

// ---- degree count + slot rank (in-degree from edges; self-loop in dinv) ----
__global__ void k_deg(const int* __restrict__ dst, int E,
                      int* __restrict__ deg, int* __restrict__ rank) {
    int i = blockIdx.x * blockDim.x + threadIdx.x;
    if (i < E) rank[i] = atomicAdd(deg + dst[i], 1);
}

__global__ void k_dinv(const int* __restrict__ deg, float* __restrict__ dinv, int n) {
    int i = blockIdx.x * blockDim.x + threadIdx.x;
    if (i < n) dinv[i] = 1.0f / sqrtf((float)deg[i] + 1.0f);
}

// ---- exclusive scan of deg -> rowstart (2-level, 1024 elems/block) ----
__global__ __launch_bounds__(256) void k_scan1(const int* __restrict__ deg,
                                               int* __restrict__ excl,
                                               int* __restrict__ bsum, int n) {
    __shared__ int tmp[256];
    int b = blockIdx.x, t = threadIdx.x;
    int base = b * 1024 + t * 4;
    int v[4];
#pragma unroll
    for (int j = 0; j < 4; ++j) v[j] = (base + j < n) ? deg[base + j] : 0;
    int s = v[0] + v[1] + v[2] + v[3];
    tmp[t] = s;
    __syncthreads();
    for (int off = 1; off < 256; off <<= 1) {
        int x = (t >= off) ? tmp[t - off] : 0;
        __syncthreads();
        tmp[t] += x;
        __syncthreads();
    }
    int run = tmp[t] - s;  // exclusive prefix within block
#pragma unroll
    for (int j = 0; j < 4; ++j) {
        if (base + j < n) excl[base + j] = run;
        run += v[j];
    }
    if (t == 255) bsum[b] = tmp[255];
}

__global__ void k_scan2(int* __restrict__ bsum, int nb) {
    if (threadIdx.x == 0) {
        int run = 0;
        for (int i = 0; i < nb; ++i) { int v = bsum[i]; bsum[i] = run; run += v; }
    }
}

__global__ void k_scan3(const int* __restrict__ excl, const int* __restrict__ bsum,
                        int* __restrict__ rowstart, int n, int E) {
    int i = blockIdx.x * blockDim.x + threadIdx.x;
    if (i < n) rowstart[i] = excl[i] + bsum[i >> 10];
    if (i == 0) rowstart[n] = E;
}

// ---- CSR fill (atomic-free): col[rowstart[d]+rank[e]] = src[e] ----
__global__ void k_fill(const int* __restrict__ src, const int* __restrict__ dst,
                       const int* __restrict__ rank, const int* __restrict__ rowstart,
                       int* __restrict__ col, int E) {
    int e = blockIdx.x * blockDim.x + threadIdx.x;
    if (e >= E) return;
    col[rowstart[dst[e]] + rank[e]] = src[e];
}

// ---- GEMM: out[n,64] = (A[n,K] @ W[K,64]) * dinv[row]
// 8 rows per wave; A[row][k] is wave-uniform -> scalar loads (SMEM pipe,
// no LDS staging). W per-lane col from LDS (b32, 2-way alias = free).
template<int K>
__global__ __launch_bounds__(256) void k_gemm(const float* __restrict__ A,
                                              const float* __restrict__ W,
                                              const float* __restrict__ dinv,
                                              float* __restrict__ out, int n) {
    __shared__ float Ws[K * HID];
    for (int i = threadIdx.x; i < K * HID; i += 256) Ws[i] = W[i];
    __syncthreads();
    const int wave = threadIdx.x >> 6, lane = threadIdx.x & 63;
    int row0 = __builtin_amdgcn_readfirstlane((blockIdx.x * 4 + wave) * 8);
    if (row0 >= n) return;
    if (row0 + 8 > n) row0 = n - 8;  // uniform clamp; duplicate rows benign
    const float* __restrict__ Ab = A + (size_t)row0 * K;

    float acc[8] = {0.f, 0.f, 0.f, 0.f, 0.f, 0.f, 0.f, 0.f};
#pragma unroll 2
    for (int k4 = 0; k4 < K / 4; ++k4) {
        const float w0 = Ws[(k4 * 4 + 0) * HID + lane];
        const float w1 = Ws[(k4 * 4 + 1) * HID + lane];
        const float w2 = Ws[(k4 * 4 + 2) * HID + lane];
        const float w3 = Ws[(k4 * 4 + 3) * HID + lane];
#pragma unroll
        for (int r = 0; r < 8; ++r) {
            float4 av = *(const float4*)(Ab + (size_t)r * K + k4 * 4);
            float t0 = fmaf(av.x, w0, acc[r]);
            float t1 = fmaf(av.y, w1, t0);
            float t2 = fmaf(av.z, w2, t1);
            acc[r] = fmaf(av.w, w3, t2);
        }
    }
#pragma unroll
    for (int r = 0; r < 8; ++r) {
        int row = row0 + r;
        out[(size_t)row * HID + lane] = acc[r] * dinv[row];
    }
}

// ---- CSR gather, 8-deep pipeline, hs pre-scaled by dinv, relu fused:
// out[i,:] = relu(b + dinv[i] * (hs[i,:] + sum_j hs[col[j],:])) ----
__global__ __launch_bounds__(256) void k_gather(const float* __restrict__ hs,
                                                const int* __restrict__ rowstart,
                                                const int* __restrict__ col,
                                                const float* __restrict__ dinv,
                                                const float* __restrict__ bias,
                                                float* __restrict__ out, int n) {
    const int wave = threadIdx.x >> 6, lane = threadIdx.x & 63;
    const int node = __builtin_amdgcn_readfirstlane(blockIdx.x * 4 + wave);
    if (node >= n) return;
    float di = dinv[node];
    float acc = hs[(size_t)node * HID + lane];
    float acc2 = 0.f;
    int j = rowstart[node], end = rowstart[node + 1];

    // full chunks of 8: scalar metadata loads, 8 independent row loads in flight
    while (end - j >= 8) {
        const int jb = __builtin_amdgcn_readfirstlane(j);
        int c[8];
#pragma unroll
        for (int t = 0; t < 8; ++t) c[t] = col[jb + t];
        float v[8];
#pragma unroll
        for (int t = 0; t < 8; ++t) v[t] = hs[(size_t)c[t] * HID + lane];
#pragma unroll
        for (int t = 0; t < 8; ++t) {
            if (t & 1) acc2 += v[t];
            else       acc  += v[t];
        }
        j += 8;
    }
    // tail (<8)
    for (; j + 1 < end; j += 2) {
        int c0 = col[j], c1 = col[j + 1];
        acc  += hs[(size_t)c0 * HID + lane];
        acc2 += hs[(size_t)c1 * HID + lane];
    }
    if (j < end) acc += hs[(size_t)col[j] * HID + lane];
    out[(size_t)node * HID + lane] = fmaxf(fmaf(acc + acc2, di, bias[lane]), 0.f);
}

// ---- mean pool per graph (batch sorted): block per graph, float4 lanes ----
__global__ __launch_bounds__(256) void k_pool(const float* __restrict__ h,
                                              const int* __restrict__ batch,
                                              float* __restrict__ gm, int n) {
    int g = blockIdx.x;
    int lo = 0, hi = n;
    while (lo < hi) { int m = (lo + hi) >> 1; if (batch[m] < g) lo = m + 1; else hi = m; }
    int lo2 = lo, hi2 = n;
    while (lo2 < hi2) { int m = (lo2 + hi2) >> 1; if (batch[m] < g + 1) lo2 = m + 1; else hi2 = m; }
    const int t = threadIdx.x;
    const int rg = t >> 4;          // 16 row slots
    const int c4 = (t & 15) * 4;    // 16 col chunks of 4
    float4 acc = make_float4(0.f, 0.f, 0.f, 0.f);
    for (int r = lo + rg; r < lo2; r += 16) {
        float4 v = *(const float4*)(h + (size_t)r * HID + c4);
        acc.x += v.x; acc.y += v.y; acc.z += v.z; acc.w += v.w;  // already relu'd
    }
    __shared__ float4 red[16][16];
    red[rg][t & 15] = acc;
    __syncthreads();
    if (t < 16) {
        float4 s = red[0][t];
#pragma unroll
        for (int g2 = 1; g2 < 16; ++g2) {
            float4 v = red[g2][t];
            s.x += v.x; s.y += v.y; s.z += v.z; s.w += v.w;
        }
        float cnt = fmaxf((float)(lo2 - lo), 1.0f);
        float inv = 1.0f / cnt;
        float* o = gm + g * HID + t * 4;
        o[0] = s.x * inv; o[1] = s.y * inv; o[2] = s.z * inv; o[3] = s.w * inv;
    }
}

// ---- MLP head ----
__global__ void k_head(const float* __restrict__ gm, const float* __restrict__ Wc1,
                       const float* __restrict__ bc1, const float* __restrict__ Wc2,
                       const float* __restrict__ bc2, float* __restrict__ outp) {
    int g = threadIdx.x;
    if (g >= NG) return;
    float o = bc2[0];
    for (int j = 0; j < 32; ++j) {
        float z = bc1[j];
        for (int k = 0; k < HID; ++k) z = fmaf(gm[g * HID + k], Wc1[k * 32 + j], z);
        o = fmaf(fmaxf(z, 0.f), Wc2[j], o);
    }
    outp[g] = o;
}

extern "C" void kernel_launch(void* const* d_in, const int* in_sizes, int n_in,
                              void* d_out, int out_size, void* d_ws, size_t ws_size,
                              hipStream_t stream) {
    const float* x    = (const float*)d_in[0];
    const int*   ei   = (const int*)d_in[1];
    const int*   batch= (const int*)d_in[2];
    const float* W1   = (const float*)d_in[3];
    const float* b1   = (const float*)d_in[4];
    const float* W2   = (const float*)d_in[5];
    const float* b2   = (const float*)d_in[6];
    const float* Wc1  = (const float*)d_in[7];
    const float* bc1  = (const float*)d_in[8];
    const float* Wc2  = (const float*)d_in[9];
    const float* bc2  = (const float*)d_in[10];

    const int E = in_sizes[1] / 2;
    const int n = in_sizes[0] / 128;   // 50000 nodes
    const int* srcp = ei;
    const int* dstp = ei + E;
    const int nb = (n + 1023) / 1024;

    char* ws = (char*)d_ws;
    auto alloc = [&](size_t bytes) {
        char* p = ws;
        ws += (bytes + 255) & ~(size_t)255;
        return p;
    };
    int*   deg      = (int*)  alloc((size_t)n * 4);
    float* dinv     = (float*)alloc((size_t)n * 4);
    int*   excl     = (int*)  alloc((size_t)n * 4);
    int*   bsum     = (int*)  alloc((size_t)nb * 4);
    int*   rowstart = (int*)  alloc((size_t)(n + 1) * 4);
    int*   rank     = (int*)  alloc((size_t)E * 4);
    int*   col      = (int*)  alloc((size_t)E * 4);
    float* bufA     = (float*)alloc((size_t)n * HID * 4);
    float* bufB     = (float*)alloc((size_t)n * HID * 4);
    float* gm       = (float*)alloc((size_t)NG * HID * 4);

    hipMemsetAsync(deg, 0, (size_t)n * 4, stream);

    // CSR build (shared by both layers)
    k_deg  <<<(E + 255) / 256, 256, 0, stream>>>(dstp, E, deg, rank);
    k_dinv <<<(n + 255) / 256, 256, 0, stream>>>(deg, dinv, n);
    k_scan1<<<nb, 256, 0, stream>>>(deg, excl, bsum, n);
    k_scan2<<<1, 64, 0, stream>>>(bsum, nb);
    k_scan3<<<(n + 255) / 256, 256, 0, stream>>>(excl, bsum, rowstart, n, E);
    k_fill <<<(E + 255) / 256, 256, 0, stream>>>(srcp, dstp, rank, rowstart, col, E);

    const int tiles = (n + 7) / 8;
    const int gblocks = (tiles + 3) / 4;

    // Layer 1 (GEMM output pre-scaled by dinv; gather applies dinv+bias+relu)
    k_gemm<128><<<gblocks, 256, 0, stream>>>(x, W1, dinv, bufA, n);
    k_gather<<<(n + 3) / 4, 256, 0, stream>>>(bufA, rowstart, col, dinv, b1, bufB, n);

    // Layer 2 (input already relu'd by gather1)
    k_gemm<64><<<gblocks, 256, 0, stream>>>(bufB, W2, dinv, bufA, n);
    k_gather<<<(n + 3) / 4, 256, 0, stream>>>(bufA, rowstart, col, dinv, b2, bufB, n);

    // Pool (input already relu'd) + head
    k_pool<<<NG, 256, 0, stream>>>(bufB, batch, gm, n);
    k_head<<<1, 64, 0, stream>>>(gm, Wc1, bc1, Wc2, bc2, (float*)d_out);
}

// Round 7
// 230.957 us; speedup vs baseline: 6.9206x; 1.0282x over previous
//
#include <hip/hip_runtime.h>
#include <math.h>

#define NG 64
#define HID 64

typedef __attribute__((ext_vector_type(8))) short bf16x8;
typedef __attribute__((ext_vector_type(4))) float f32x4;

// RNE f32 -> bf16 bit helpers (data is finite; no NaN handling needed)
__device__ __forceinline__ unsigned int bfbits(float f) {
    unsigned int u = __float_as_uint(f);
    return (u + 0x7FFFu + ((u >> 16) & 1u)) >> 16;
}
__device__ __forceinline__ float bfval(unsigned int bits) {
    return __uint_as_float(bits << 16);
}

// ---- degree count + slot rank (in-degree from edges; self-loop in dinv) ----
__global__ void k_deg(const int* __restrict__ dst, int E,
                      int* __restrict__ deg, int* __restrict__ rank) {
    int i = blockIdx.x * blockDim.x + threadIdx.x;
    if (i < E) rank[i] = atomicAdd(deg + dst[i], 1);
}

__global__ void k_dinv(const int* __restrict__ deg, float* __restrict__ dinv, int n) {
    int i = blockIdx.x * blockDim.x + threadIdx.x;
    if (i < n) dinv[i] = 1.0f / sqrtf((float)deg[i] + 1.0f);
}

// ---- exclusive scan of deg -> rowstart (2-level, 1024 elems/block) ----
__global__ __launch_bounds__(256) void k_scan1(const int* __restrict__ deg,
                                               int* __restrict__ excl,
                                               int* __restrict__ bsum, int n) {
    __shared__ int tmp[256];
    int b = blockIdx.x, t = threadIdx.x;
    int base = b * 1024 + t * 4;
    int v[4];
#pragma unroll
    for (int j = 0; j < 4; ++j) v[j] = (base + j < n) ? deg[base + j] : 0;
    int s = v[0] + v[1] + v[2] + v[3];
    tmp[t] = s;
    __syncthreads();
    for (int off = 1; off < 256; off <<= 1) {
        int x = (t >= off) ? tmp[t - off] : 0;
        __syncthreads();
        tmp[t] += x;
        __syncthreads();
    }
    int run = tmp[t] - s;  // exclusive prefix within block
#pragma unroll
    for (int j = 0; j < 4; ++j) {
        if (base + j < n) excl[base + j] = run;
        run += v[j];
    }
    if (t == 255) bsum[b] = tmp[255];
}

__global__ void k_scan2(int* __restrict__ bsum, int nb) {
    if (threadIdx.x == 0) {
        int run = 0;
        for (int i = 0; i < nb; ++i) { int v = bsum[i]; bsum[i] = run; run += v; }
    }
}

__global__ void k_scan3(const int* __restrict__ excl, const int* __restrict__ bsum,
                        int* __restrict__ rowstart, int n, int E) {
    int i = blockIdx.x * blockDim.x + threadIdx.x;
    if (i < n) rowstart[i] = excl[i] + bsum[i >> 10];
    if (i == 0) rowstart[n] = E;
}

// ---- CSR fill (atomic-free): col[rowstart[d]+rank[e]] = src[e] ----
__global__ void k_fill(const int* __restrict__ src, const int* __restrict__ dst,
                       const int* __restrict__ rank, const int* __restrict__ rowstart,
                       int* __restrict__ col, int E) {
    int e = blockIdx.x * blockDim.x + threadIdx.x;
    if (e >= E) return;
    col[rowstart[dst[e]] + rank[e]] = src[e];
}

// ---- W pre-split: W[K][64] f32 -> Wt_hi/Wt_lo[c][k] bf16 bits (K-major) ----
__global__ void k_wconv(const float* __restrict__ W, unsigned short* __restrict__ Whi,
                        unsigned short* __restrict__ Wlo, int K) {
    int i = blockIdx.x * blockDim.x + threadIdx.x;
    if (i >= K * 64) return;
    int k = i >> 6, c = i & 63;
    float f = W[i];
    unsigned hb = bfbits(f);
    Whi[c * K + k] = (unsigned short)hb;
    Wlo[c * K + k] = (unsigned short)bfbits(f - bfval(hb));
}

// ---- MFMA GEMM: out[n,64] = (A[n,K] @ W[K,64]) * dinv[row]
// One wave per 16-row tile; bf16 split (hi+lo), 3 MFMAs per (ksub,coltile).
// Fragment layouts (16x16x32 bf16, HW-verified per guide §3):
//   A: row = lane&15, k = 8*(lane>>4)+e (contiguous 8)
//   B: col = lane&15, k = 8*(lane>>4)+e
//   D: col = lane&15, row = 4*(lane>>4)+reg
template<int K>
__global__ __launch_bounds__(256) void k_gemm_mfma(const float* __restrict__ A,
                                                   const unsigned short* __restrict__ Whi,
                                                   const unsigned short* __restrict__ Wlo,
                                                   const float* __restrict__ dinv,
                                                   float* __restrict__ out, int n) {
    const int wave = threadIdx.x >> 6, lane = threadIdx.x & 63;
    const int ntiles = (n + 15) >> 4;
    const int tile = blockIdx.x * 4 + wave;
    if (tile >= ntiles) return;
    const int lrow = lane & 15;   // A-row within tile / D-col within coltile
    const int kgrp = lane >> 4;   // 0..3
    const int arow = tile * 16 + lrow;

    f32x4 acc[4];
#pragma unroll
    for (int ct = 0; ct < 4; ++ct) acc[ct] = (f32x4){0.f, 0.f, 0.f, 0.f};

#pragma unroll
    for (int s = 0; s < K / 32; ++s) {
        // A fragment: 8 contiguous f32 -> split into hi/lo bf16
        const float* ap = A + (size_t)arow * K + s * 32 + kgrp * 8;
        float4 v0, v1;
        if (arow < n) { v0 = *(const float4*)ap; v1 = *(const float4*)(ap + 4); }
        else { v0 = make_float4(0.f,0.f,0.f,0.f); v1 = v0; }
        float av[8] = {v0.x, v0.y, v0.z, v0.w, v1.x, v1.y, v1.z, v1.w};
        bf16x8 ahi, alo;
#pragma unroll
        for (int e = 0; e < 8; ++e) {
            unsigned hb = bfbits(av[e]);
            ahi[e] = (short)hb;
            alo[e] = (short)bfbits(av[e] - bfval(hb));
        }
#pragma unroll
        for (int ct = 0; ct < 4; ++ct) {
            const size_t wo = (size_t)(ct * 16 + lrow) * K + s * 32 + kgrp * 8;
            bf16x8 whi = *(const bf16x8*)(Whi + wo);
            bf16x8 wlo = *(const bf16x8*)(Wlo + wo);
            acc[ct] = __builtin_amdgcn_mfma_f32_16x16x32_bf16(ahi, whi, acc[ct], 0, 0, 0);
            acc[ct] = __builtin_amdgcn_mfma_f32_16x16x32_bf16(alo, whi, acc[ct], 0, 0, 0);
            acc[ct] = __builtin_amdgcn_mfma_f32_16x16x32_bf16(ahi, wlo, acc[ct], 0, 0, 0);
        }
    }

#pragma unroll
    for (int r = 0; r < 4; ++r) {
        int orow = tile * 16 + kgrp * 4 + r;
        if (orow < n) {
            float dv = dinv[orow];
#pragma unroll
            for (int ct = 0; ct < 4; ++ct)
                out[(size_t)orow * HID + ct * 16 + lrow] = acc[ct][r] * dv;
        }
    }
}

// ---- CSR gather, 8-deep pipeline, hs pre-scaled by dinv, relu fused:
// out[i,:] = relu(b + dinv[i] * (hs[i,:] + sum_j hs[col[j],:])) ----
__global__ __launch_bounds__(256) void k_gather(const float* __restrict__ hs,
                                                const int* __restrict__ rowstart,
                                                const int* __restrict__ col,
                                                const float* __restrict__ dinv,
                                                const float* __restrict__ bias,
                                                float* __restrict__ out, int n) {
    const int wave = threadIdx.x >> 6, lane = threadIdx.x & 63;
    const int node = __builtin_amdgcn_readfirstlane(blockIdx.x * 4 + wave);
    if (node >= n) return;
    float di = dinv[node];
    float acc = hs[(size_t)node * HID + lane];
    float acc2 = 0.f;
    int j = rowstart[node], end = rowstart[node + 1];

    while (end - j >= 8) {
        const int jb = __builtin_amdgcn_readfirstlane(j);
        int c[8];
#pragma unroll
        for (int t = 0; t < 8; ++t) c[t] = col[jb + t];
        float v[8];
#pragma unroll
        for (int t = 0; t < 8; ++t) v[t] = hs[(size_t)c[t] * HID + lane];
#pragma unroll
        for (int t = 0; t < 8; ++t) {
            if (t & 1) acc2 += v[t];
            else       acc  += v[t];
        }
        j += 8;
    }
    for (; j + 1 < end; j += 2) {
        int c0 = col[j], c1 = col[j + 1];
        acc  += hs[(size_t)c0 * HID + lane];
        acc2 += hs[(size_t)c1 * HID + lane];
    }
    if (j < end) acc += hs[(size_t)col[j] * HID + lane];
    out[(size_t)node * HID + lane] = fmaxf(fmaf(acc + acc2, di, bias[lane]), 0.f);
}

// ---- mean pool per graph (batch sorted): block per graph, float4 lanes ----
__global__ __launch_bounds__(256) void k_pool(const float* __restrict__ h,
                                              const int* __restrict__ batch,
                                              float* __restrict__ gm, int n) {
    int g = blockIdx.x;
    int lo = 0, hi = n;
    while (lo < hi) { int m = (lo + hi) >> 1; if (batch[m] < g) lo = m + 1; else hi = m; }
    int lo2 = lo, hi2 = n;
    while (lo2 < hi2) { int m = (lo2 + hi2) >> 1; if (batch[m] < g + 1) lo2 = m + 1; else hi2 = m; }
    const int t = threadIdx.x;
    const int rg = t >> 4;          // 16 row slots
    const int c4 = (t & 15) * 4;    // 16 col chunks of 4
    float4 acc = make_float4(0.f, 0.f, 0.f, 0.f);
    for (int r = lo + rg; r < lo2; r += 16) {
        float4 v = *(const float4*)(h + (size_t)r * HID + c4);
        acc.x += v.x; acc.y += v.y; acc.z += v.z; acc.w += v.w;  // already relu'd
    }
    __shared__ float4 red[16][16];
    red[rg][t & 15] = acc;
    __syncthreads();
    if (t < 16) {
        float4 s = red[0][t];
#pragma unroll
        for (int g2 = 1; g2 < 16; ++g2) {
            float4 v = red[g2][t];
            s.x += v.x; s.y += v.y; s.z += v.z; s.w += v.w;
        }
        float cnt = fmaxf((float)(lo2 - lo), 1.0f);
        float inv = 1.0f / cnt;
        float* o = gm + g * HID + t * 4;
        o[0] = s.x * inv; o[1] = s.y * inv; o[2] = s.z * inv; o[3] = s.w * inv;
    }
}

// ---- MLP head ----
__global__ void k_head(const float* __restrict__ gm, const float* __restrict__ Wc1,
                       const float* __restrict__ bc1, const float* __restrict__ Wc2,
                       const float* __restrict__ bc2, float* __restrict__ outp) {
    int g = threadIdx.x;
    if (g >= NG) return;
    float o = bc2[0];
    for (int j = 0; j < 32; ++j) {
        float z = bc1[j];
        for (int k = 0; k < HID; ++k) z = fmaf(gm[g * HID + k], Wc1[k * 32 + j], z);
        o = fmaf(fmaxf(z, 0.f), Wc2[j], o);
    }
    outp[g] = o;
}

extern "C" void kernel_launch(void* const* d_in, const int* in_sizes, int n_in,
                              void* d_out, int out_size, void* d_ws, size_t ws_size,
                              hipStream_t stream) {
    const float* x    = (const float*)d_in[0];
    const int*   ei   = (const int*)d_in[1];
    const int*   batch= (const int*)d_in[2];
    const float* W1   = (const float*)d_in[3];
    const float* b1   = (const float*)d_in[4];
    const float* W2   = (const float*)d_in[5];
    const float* b2   = (const float*)d_in[6];
    const float* Wc1  = (const float*)d_in[7];
    const float* bc1  = (const float*)d_in[8];
    const float* Wc2  = (const float*)d_in[9];
    const float* bc2  = (const float*)d_in[10];

    const int E = in_sizes[1] / 2;
    const int n = in_sizes[0] / 128;   // 50000 nodes
    const int* srcp = ei;
    const int* dstp = ei + E;
    const int nb = (n + 1023) / 1024;

    char* ws = (char*)d_ws;
    auto alloc = [&](size_t bytes) {
        char* p = ws;
        ws += (bytes + 255) & ~(size_t)255;
        return p;
    };
    int*   deg      = (int*)  alloc((size_t)n * 4);
    float* dinv     = (float*)alloc((size_t)n * 4);
    int*   excl     = (int*)  alloc((size_t)n * 4);
    int*   bsum     = (int*)  alloc((size_t)nb * 4);
    int*   rowstart = (int*)  alloc((size_t)(n + 1) * 4);
    int*   rank     = (int*)  alloc((size_t)E * 4);
    int*   col      = (int*)  alloc((size_t)E * 4);
    float* bufA     = (float*)alloc((size_t)n * HID * 4);
    float* bufB     = (float*)alloc((size_t)n * HID * 4);
    float* gm       = (float*)alloc((size_t)NG * HID * 4);
    unsigned short* W1hi = (unsigned short*)alloc(128 * 64 * 2);
    unsigned short* W1lo = (unsigned short*)alloc(128 * 64 * 2);
    unsigned short* W2hi = (unsigned short*)alloc(64 * 64 * 2);
    unsigned short* W2lo = (unsigned short*)alloc(64 * 64 * 2);

    hipMemsetAsync(deg, 0, (size_t)n * 4, stream);

    // CSR build (shared by both layers) + W pre-split
    k_deg  <<<(E + 255) / 256, 256, 0, stream>>>(dstp, E, deg, rank);
    k_dinv <<<(n + 255) / 256, 256, 0, stream>>>(deg, dinv, n);
    k_scan1<<<nb, 256, 0, stream>>>(deg, excl, bsum, n);
    k_scan2<<<1, 64, 0, stream>>>(bsum, nb);
    k_scan3<<<(n + 255) / 256, 256, 0, stream>>>(excl, bsum, rowstart, n, E);
    k_fill <<<(E + 255) / 256, 256, 0, stream>>>(srcp, dstp, rank, rowstart, col, E);
    k_wconv<<<(128 * 64 + 255) / 256, 256, 0, stream>>>(W1, W1hi, W1lo, 128);
    k_wconv<<<(64 * 64 + 255) / 256, 256, 0, stream>>>(W2, W2hi, W2lo, 64);

    const int ntiles = (n + 15) / 16;
    const int mblocks = (ntiles + 3) / 4;

    // Layer 1 (GEMM output pre-scaled by dinv; gather applies dinv+bias+relu)
    k_gemm_mfma<128><<<mblocks, 256, 0, stream>>>(x, W1hi, W1lo, dinv, bufA, n);
    k_gather<<<(n + 3) / 4, 256, 0, stream>>>(bufA, rowstart, col, dinv, b1, bufB, n);

    // Layer 2 (input already relu'd by gather1)
    k_gemm_mfma<64><<<mblocks, 256, 0, stream>>>(bufB, W2hi, W2lo, dinv, bufA, n);
    k_gather<<<(n + 3) / 4, 256, 0, stream>>>(bufA, rowstart, col, dinv, b2, bufB, n);

    // Pool (input already relu'd) + head
    k_pool<<<NG, 256, 0, stream>>>(bufB, batch, gm, n);
    k_head<<<1, 64, 0, stream>>>(gm, Wc1, bc1, Wc2, bc2, (float*)d_out);
}

// Round 8
// 169.937 us; speedup vs baseline: 9.4056x; 1.3591x over previous
//
#include <hip/hip_runtime.h>
#include <math.h>

#define NG 64
#define HID 64

typedef __attribute__((ext_vector_type(8))) short bf16x8;
typedef __attribute__((ext_vector_type(4))) float f32x4;

// RNE f32 -> bf16 bit helpers (data finite; no NaN handling needed)
__device__ __forceinline__ unsigned int bfbits(float f) {
    unsigned int u = __float_as_uint(f);
    return (u + 0x7FFFu + ((u >> 16) & 1u)) >> 16;
}
__device__ __forceinline__ float bfval(unsigned int bits) {
    return __uint_as_float(bits << 16);
}

// ---- degree count + slot rank (in-degree from edges; self-loop in dinv) ----
__global__ void k_deg(const int* __restrict__ dst, int E,
                      int* __restrict__ deg, int* __restrict__ rank) {
    int i = blockIdx.x * blockDim.x + threadIdx.x;
    if (i < E) rank[i] = atomicAdd(deg + dst[i], 1);
}

// ---- scan level 1 + dinv: local exclusive prefix (1024/block) + block sums ----
__global__ __launch_bounds__(256) void k_scan1(const int* __restrict__ deg,
                                               int* __restrict__ excl,
                                               int* __restrict__ bsum,
                                               float* __restrict__ dinv, int n) {
    __shared__ int tmp[256];
    int b = blockIdx.x, t = threadIdx.x;
    int base = b * 1024 + t * 4;
    int v[4];
#pragma unroll
    for (int j = 0; j < 4; ++j) v[j] = (base + j < n) ? deg[base + j] : 0;
#pragma unroll
    for (int j = 0; j < 4; ++j)
        if (base + j < n) dinv[base + j] = 1.0f / sqrtf((float)v[j] + 1.0f);
    int s = v[0] + v[1] + v[2] + v[3];
    tmp[t] = s;
    __syncthreads();
    for (int off = 1; off < 256; off <<= 1) {
        int x = (t >= off) ? tmp[t - off] : 0;
        __syncthreads();
        tmp[t] += x;
        __syncthreads();
    }
    int run = tmp[t] - s;  // exclusive prefix within block
#pragma unroll
    for (int j = 0; j < 4; ++j) {
        if (base + j < n) excl[base + j] = run;
        run += v[j];
    }
    if (t == 255) bsum[b] = tmp[255];
}

// ---- scan level 2+3 fused (+ graph boundary detect on sorted batch) ----
// rowstart[i] = excl[i] + prefix(bsum up to segment); gstart[g] = lower_bound(batch, g)
__global__ __launch_bounds__(256) void k_scan23(const int* __restrict__ excl,
                                                const int* __restrict__ bsum,
                                                const int* __restrict__ batch,
                                                int* __restrict__ rowstart,
                                                int* __restrict__ gstart,
                                                int n, int E, int nb) {
    __shared__ int bs[256];
    __shared__ int pre;
    const int t = threadIdx.x;
    if (t < nb) bs[t] = bsum[t];
    __syncthreads();
    if (t == 0) {
        int seg = (blockIdx.x * 256) >> 10;  // one segment per 256-block (256 | 1024)
        int s = 0;
        for (int b = 0; b < seg; ++b) s += bs[b];
        pre = s;
    }
    __syncthreads();
    int i = blockIdx.x * 256 + t;
    if (i < n) {
        rowstart[i] = excl[i] + pre;
        int bi = batch[i];
        int bp = (i == 0) ? -1 : batch[i - 1];
        for (int g = bp + 1; g <= bi; ++g) gstart[g] = i;
        if (i == n - 1)
            for (int g = bi + 1; g <= NG; ++g) gstart[g] = n;
    }
    if (i == 0) rowstart[n] = E;
}

// ---- CSR fill (atomic-free): col[rowstart[d]+rank[e]] = src[e] ----
__global__ void k_fill(const int* __restrict__ src, const int* __restrict__ dst,
                       const int* __restrict__ rank, const int* __restrict__ rowstart,
                       int* __restrict__ col, int E) {
    int e = blockIdx.x * blockDim.x + threadIdx.x;
    if (e >= E) return;
    col[rowstart[dst[e]] + rank[e]] = src[e];
}

// ---- W pre-split (both layers, one launch): f32 -> hi/lo bf16, K-major ----
__global__ void k_wconv(const float* __restrict__ W1, const float* __restrict__ W2,
                        unsigned short* __restrict__ W1hi, unsigned short* __restrict__ W1lo,
                        unsigned short* __restrict__ W2hi, unsigned short* __restrict__ W2lo) {
    int i = blockIdx.x * blockDim.x + threadIdx.x;
    if (i < 128 * 64) {
        int k = i >> 6, c = i & 63;
        float f = W1[i];
        unsigned hb = bfbits(f);
        W1hi[c * 128 + k] = (unsigned short)hb;
        W1lo[c * 128 + k] = (unsigned short)bfbits(f - bfval(hb));
    }
    int i2 = i - 128 * 64;
    if (i2 >= 0 && i2 < 64 * 64) {
        int k = i2 >> 6, c = i2 & 63;
        float f = W2[i2];
        unsigned hb = bfbits(f);
        W2hi[c * 64 + k] = (unsigned short)hb;
        W2lo[c * 64 + k] = (unsigned short)bfbits(f - bfval(hb));
    }
}

// ---- MFMA GEMM: out[n,64] = (A[n,K] @ W[K,64]) * dinv[row]
// 32 rows (2 sub-tiles) per wave: W fragments loaded once, used by both.
// bf16 split (hi+lo): 3 MFMAs per (subtile, ksub, coltile); error ~2^-17.
// Fragment layouts (16x16x32 bf16, HW-verified): A row=lane&15, k=8*(lane>>4)+e;
// D col=lane&15, row=4*(lane>>4)+reg.
template<int K>
__global__ __launch_bounds__(256) void k_gemm_mfma(const float* __restrict__ A,
                                                   const unsigned short* __restrict__ Whi,
                                                   const unsigned short* __restrict__ Wlo,
                                                   const float* __restrict__ dinv,
                                                   float* __restrict__ out, int n) {
    const int wave = threadIdx.x >> 6, lane = threadIdx.x & 63;
    const int ntile2 = (n + 31) >> 5;
    const int tile2 = blockIdx.x * 4 + wave;
    if (tile2 >= ntile2) return;
    const int lrow = lane & 15;
    const int kgrp = lane >> 4;
    const int r0 = tile2 * 32 + lrow;
    const int r1 = r0 + 16;

    f32x4 acc0[4], acc1[4];
#pragma unroll
    for (int ct = 0; ct < 4; ++ct) {
        acc0[ct] = (f32x4){0.f, 0.f, 0.f, 0.f};
        acc1[ct] = (f32x4){0.f, 0.f, 0.f, 0.f};
    }

#pragma unroll
    for (int s = 0; s < K / 32; ++s) {
        float a0[8], a1[8];
        {
            const float* p0 = A + (size_t)r0 * K + s * 32 + kgrp * 8;
            const float* p1 = A + (size_t)r1 * K + s * 32 + kgrp * 8;
            float4 u0, u1, w0, w1;
            if (r0 < n) { u0 = *(const float4*)p0; u1 = *(const float4*)(p0 + 4); }
            else { u0 = make_float4(0.f,0.f,0.f,0.f); u1 = u0; }
            if (r1 < n) { w0 = *(const float4*)p1; w1 = *(const float4*)(p1 + 4); }
            else { w0 = make_float4(0.f,0.f,0.f,0.f); w1 = w0; }
            a0[0]=u0.x; a0[1]=u0.y; a0[2]=u0.z; a0[3]=u0.w;
            a0[4]=u1.x; a0[5]=u1.y; a0[6]=u1.z; a0[7]=u1.w;
            a1[0]=w0.x; a1[1]=w0.y; a1[2]=w0.z; a1[3]=w0.w;
            a1[4]=w1.x; a1[5]=w1.y; a1[6]=w1.z; a1[7]=w1.w;
        }
        bf16x8 ahi0, alo0, ahi1, alo1;
#pragma unroll
        for (int e = 0; e < 8; ++e) {
            unsigned hb0 = bfbits(a0[e]);
            ahi0[e] = (short)hb0;
            alo0[e] = (short)bfbits(a0[e] - bfval(hb0));
            unsigned hb1 = bfbits(a1[e]);
            ahi1[e] = (short)hb1;
            alo1[e] = (short)bfbits(a1[e] - bfval(hb1));
        }
#pragma unroll
        for (int ct = 0; ct < 4; ++ct) {
            const size_t wo = (size_t)(ct * 16 + lrow) * K + s * 32 + kgrp * 8;
            bf16x8 whi = *(const bf16x8*)(Whi + wo);
            bf16x8 wlo = *(const bf16x8*)(Wlo + wo);
            acc0[ct] = __builtin_amdgcn_mfma_f32_16x16x32_bf16(ahi0, whi, acc0[ct], 0, 0, 0);
            acc0[ct] = __builtin_amdgcn_mfma_f32_16x16x32_bf16(alo0, whi, acc0[ct], 0, 0, 0);
            acc0[ct] = __builtin_amdgcn_mfma_f32_16x16x32_bf16(ahi0, wlo, acc0[ct], 0, 0, 0);
            acc1[ct] = __builtin_amdgcn_mfma_f32_16x16x32_bf16(ahi1, whi, acc1[ct], 0, 0, 0);
            acc1[ct] = __builtin_amdgcn_mfma_f32_16x16x32_bf16(alo1, whi, acc1[ct], 0, 0, 0);
            acc1[ct] = __builtin_amdgcn_mfma_f32_16x16x32_bf16(ahi1, wlo, acc1[ct], 0, 0, 0);
        }
    }

#pragma unroll
    for (int r = 0; r < 4; ++r) {
        int o0 = tile2 * 32 + kgrp * 4 + r;
        if (o0 < n) {
            float dv = dinv[o0];
#pragma unroll
            for (int ct = 0; ct < 4; ++ct)
                out[(size_t)o0 * HID + ct * 16 + lrow] = acc0[ct][r] * dv;
        }
        int o1 = o0 + 16;
        if (o1 < n) {
            float dv = dinv[o1];
#pragma unroll
            for (int ct = 0; ct < 4; ++ct)
                out[(size_t)o1 * HID + ct * 16 + lrow] = acc1[ct][r] * dv;
        }
    }
}

// ---- CSR gather: 2 nodes per wave, dual 8-deep pipelines (16 loads in flight)
// out[i,:] = relu(b + dinv[i] * (hs[i,:] + sum_j hs[col[j],:])) ----
__global__ __launch_bounds__(256) void k_gather(const float* __restrict__ hs,
                                                const int* __restrict__ rowstart,
                                                const int* __restrict__ col,
                                                const float* __restrict__ dinv,
                                                const float* __restrict__ bias,
                                                float* __restrict__ out, int n) {
    const int wave = threadIdx.x >> 6, lane = threadIdx.x & 63;
    const int n0 = blockIdx.x * 8 + wave * 2;
    if (n0 >= n) return;
    const int n1 = n0 + 1;
    const bool has1 = (n1 < n);
    const float bl = bias[lane];

    float di0 = dinv[n0];
    float acc0 = hs[(size_t)n0 * HID + lane], acc0b = 0.f;
    int j0 = rowstart[n0], e0 = rowstart[n0 + 1];
    float di1 = 0.f, acc1 = 0.f, acc1b = 0.f;
    int j1 = 0, e1 = 0;
    if (has1) {
        di1 = dinv[n1];
        acc1 = hs[(size_t)n1 * HID + lane];
        j1 = e0;                 // rowstart[n1] == rowstart[n0+1]
        e1 = rowstart[n1 + 1];
    }

    // joint chunks: 16 independent row loads in flight
    while (e0 - j0 >= 8 && e1 - j1 >= 8) {
        const int jb0 = __builtin_amdgcn_readfirstlane(j0);
        const int jb1 = __builtin_amdgcn_readfirstlane(j1);
        int c0[8], c1[8];
#pragma unroll
        for (int t = 0; t < 8; ++t) c0[t] = col[jb0 + t];
#pragma unroll
        for (int t = 0; t < 8; ++t) c1[t] = col[jb1 + t];
        float v0[8], v1[8];
#pragma unroll
        for (int t = 0; t < 8; ++t) v0[t] = hs[(size_t)c0[t] * HID + lane];
#pragma unroll
        for (int t = 0; t < 8; ++t) v1[t] = hs[(size_t)c1[t] * HID + lane];
#pragma unroll
        for (int t = 0; t < 8; ++t) { if (t & 1) acc0b += v0[t]; else acc0 += v0[t]; }
#pragma unroll
        for (int t = 0; t < 8; ++t) { if (t & 1) acc1b += v1[t]; else acc1 += v1[t]; }
        j0 += 8; j1 += 8;
    }
    // drain node0
    while (e0 - j0 >= 8) {
        const int jb = __builtin_amdgcn_readfirstlane(j0);
        int c[8];
#pragma unroll
        for (int t = 0; t < 8; ++t) c[t] = col[jb + t];
        float v[8];
#pragma unroll
        for (int t = 0; t < 8; ++t) v[t] = hs[(size_t)c[t] * HID + lane];
#pragma unroll
        for (int t = 0; t < 8; ++t) { if (t & 1) acc0b += v[t]; else acc0 += v[t]; }
        j0 += 8;
    }
    // drain node1
    while (e1 - j1 >= 8) {
        const int jb = __builtin_amdgcn_readfirstlane(j1);
        int c[8];
#pragma unroll
        for (int t = 0; t < 8; ++t) c[t] = col[jb + t];
        float v[8];
#pragma unroll
        for (int t = 0; t < 8; ++t) v[t] = hs[(size_t)c[t] * HID + lane];
#pragma unroll
        for (int t = 0; t < 8; ++t) { if (t & 1) acc1b += v[t]; else acc1 += v[t]; }
        j1 += 8;
    }
    for (; j0 + 1 < e0; j0 += 2) {
        acc0  += hs[(size_t)col[j0] * HID + lane];
        acc0b += hs[(size_t)col[j0 + 1] * HID + lane];
    }
    if (j0 < e0) acc0 += hs[(size_t)col[j0] * HID + lane];
    for (; j1 + 1 < e1; j1 += 2) {
        acc1  += hs[(size_t)col[j1] * HID + lane];
        acc1b += hs[(size_t)col[j1 + 1] * HID + lane];
    }
    if (j1 < e1) acc1 += hs[(size_t)col[j1] * HID + lane];

    out[(size_t)n0 * HID + lane] = fmaxf(fmaf(acc0 + acc0b, di0, bl), 0.f);
    if (has1)
        out[(size_t)n1 * HID + lane] = fmaxf(fmaf(acc1 + acc1b, di1, bl), 0.f);
}

// ---- fused mean-pool + MLP head: block g -> out[g] (h already relu'd) ----
__global__ __launch_bounds__(512) void k_poolhead(const float* __restrict__ h,
                                                  const int* __restrict__ gstart,
                                                  const float* __restrict__ Wc1,
                                                  const float* __restrict__ bc1,
                                                  const float* __restrict__ Wc2,
                                                  const float* __restrict__ bc2,
                                                  float* __restrict__ outp, int n) {
    const int g = blockIdx.x;
    const int lo = gstart[g], lo2 = gstart[g + 1];
    const int t = threadIdx.x;
    const int rg = t >> 4;          // 32 row slots
    const int c4 = (t & 15) * 4;    // 16 col chunks of 4
    float4 acc = make_float4(0.f, 0.f, 0.f, 0.f);
    for (int r = lo + rg; r < lo2; r += 32) {
        float4 v = *(const float4*)(h + (size_t)r * HID + c4);
        acc.x += v.x; acc.y += v.y; acc.z += v.z; acc.w += v.w;
    }
    __shared__ float4 red[32][16];
    __shared__ float gmv[HID];
    __shared__ float zs[32];
    red[rg][t & 15] = acc;
    __syncthreads();
    if (t < 16) {
        float4 s = red[0][t];
#pragma unroll
        for (int g2 = 1; g2 < 32; ++g2) {
            float4 v = red[g2][t];
            s.x += v.x; s.y += v.y; s.z += v.z; s.w += v.w;
        }
        float inv = 1.0f / fmaxf((float)(lo2 - lo), 1.0f);
        gmv[t * 4 + 0] = s.x * inv; gmv[t * 4 + 1] = s.y * inv;
        gmv[t * 4 + 2] = s.z * inv; gmv[t * 4 + 3] = s.w * inv;
    }
    __syncthreads();
    if (t < 32) {
        float z = bc1[t];
#pragma unroll 8
        for (int k = 0; k < HID; ++k) z = fmaf(gmv[k], Wc1[k * 32 + t], z);
        zs[t] = fmaxf(z, 0.f) * Wc2[t];
    }
    __syncthreads();
    if (t == 0) {
        float o = bc2[0];
#pragma unroll
        for (int j = 0; j < 32; ++j) o += zs[j];
        outp[g] = o;
    }
}

extern "C" void kernel_launch(void* const* d_in, const int* in_sizes, int n_in,
                              void* d_out, int out_size, void* d_ws, size_t ws_size,
                              hipStream_t stream) {
    const float* x    = (const float*)d_in[0];
    const int*   ei   = (const int*)d_in[1];
    const int*   batch= (const int*)d_in[2];
    const float* W1   = (const float*)d_in[3];
    const float* b1   = (const float*)d_in[4];
    const float* W2   = (const float*)d_in[5];
    const float* b2   = (const float*)d_in[6];
    const float* Wc1  = (const float*)d_in[7];
    const float* bc1  = (const float*)d_in[8];
    const float* Wc2  = (const float*)d_in[9];
    const float* bc2  = (const float*)d_in[10];

    const int E = in_sizes[1] / 2;
    const int n = in_sizes[0] / 128;   // 50000 nodes
    const int* srcp = ei;
    const int* dstp = ei + E;
    const int nb = (n + 1023) / 1024;

    char* ws = (char*)d_ws;
    auto alloc = [&](size_t bytes) {
        char* p = ws;
        ws += (bytes + 255) & ~(size_t)255;
        return p;
    };
    int*   deg      = (int*)  alloc((size_t)n * 4);
    float* dinv     = (float*)alloc((size_t)n * 4);
    int*   excl     = (int*)  alloc((size_t)n * 4);
    int*   bsum     = (int*)  alloc((size_t)nb * 4);
    int*   rowstart = (int*)  alloc((size_t)(n + 1) * 4);
    int*   gstart   = (int*)  alloc((size_t)(NG + 1) * 4);
    int*   rank     = (int*)  alloc((size_t)E * 4);
    int*   col      = (int*)  alloc((size_t)E * 4);
    float* bufA     = (float*)alloc((size_t)n * HID * 4);
    float* bufB     = (float*)alloc((size_t)n * HID * 4);
    unsigned short* W1hi = (unsigned short*)alloc(128 * 64 * 2);
    unsigned short* W1lo = (unsigned short*)alloc(128 * 64 * 2);
    unsigned short* W2hi = (unsigned short*)alloc(64 * 64 * 2);
    unsigned short* W2lo = (unsigned short*)alloc(64 * 64 * 2);

    hipMemsetAsync(deg, 0, (size_t)n * 4, stream);

    // CSR build (shared by both layers) + W pre-split
    k_deg   <<<(E + 255) / 256, 256, 0, stream>>>(dstp, E, deg, rank);
    k_scan1 <<<nb, 256, 0, stream>>>(deg, excl, bsum, dinv, n);
    k_scan23<<<(n + 255) / 256, 256, 0, stream>>>(excl, bsum, batch, rowstart, gstart, n, E, nb);
    k_fill  <<<(E + 255) / 256, 256, 0, stream>>>(srcp, dstp, rank, rowstart, col, E);
    k_wconv <<<(128 * 64 + 64 * 64 + 255) / 256, 256, 0, stream>>>(W1, W2, W1hi, W1lo, W2hi, W2lo);

    const int mblocks = ((n + 31) / 32 + 3) / 4;
    const int gblocks = (n + 7) / 8;

    // Layer 1 (GEMM output pre-scaled by dinv; gather applies dinv+bias+relu)
    k_gemm_mfma<128><<<mblocks, 256, 0, stream>>>(x, W1hi, W1lo, dinv, bufA, n);
    k_gather<<<gblocks, 256, 0, stream>>>(bufA, rowstart, col, dinv, b1, bufB, n);

    // Layer 2 (input already relu'd by gather1)
    k_gemm_mfma<64><<<mblocks, 256, 0, stream>>>(bufB, W2hi, W2lo, dinv, bufA, n);
    k_gather<<<gblocks, 256, 0, stream>>>(bufA, rowstart, col, dinv, b2, bufB, n);

    // Fused pool + head
    k_poolhead<<<NG, 512, 0, stream>>>(bufB, gstart, Wc1, bc1, Wc2, bc2, (float*)d_out, n);
}

// Round 9
// 162.649 us; speedup vs baseline: 9.8270x; 1.0448x over previous
//
#include <hip/hip_runtime.h>
#include <math.h>

#define NG 64
#define HID 64

typedef __attribute__((ext_vector_type(8))) short bf16x8;
typedef __attribute__((ext_vector_type(4))) float f32x4;

// RNE f32 -> bf16 bit helpers (data finite; no NaN handling needed)
__device__ __forceinline__ unsigned int bfbits(float f) {
    unsigned int u = __float_as_uint(f);
    return (u + 0x7FFFu + ((u >> 16) & 1u)) >> 16;
}
__device__ __forceinline__ float bfval(unsigned int bits) {
    return __uint_as_float(bits << 16);
}

// ---- degree count + slot rank (in-degree from edges; self-loop in dinv) ----
__global__ void k_deg(const int* __restrict__ dst, int E,
                      int* __restrict__ deg, int* __restrict__ rank) {
    int i = blockIdx.x * blockDim.x + threadIdx.x;
    if (i < E) rank[i] = atomicAdd(deg + dst[i], 1);
}

// ---- scan level 1 + dinv ----
__global__ __launch_bounds__(256) void k_scan1(const int* __restrict__ deg,
                                               int* __restrict__ excl,
                                               int* __restrict__ bsum,
                                               float* __restrict__ dinv, int n) {
    __shared__ int tmp[256];
    int b = blockIdx.x, t = threadIdx.x;
    int base = b * 1024 + t * 4;
    int v[4];
#pragma unroll
    for (int j = 0; j < 4; ++j) v[j] = (base + j < n) ? deg[base + j] : 0;
#pragma unroll
    for (int j = 0; j < 4; ++j)
        if (base + j < n) dinv[base + j] = 1.0f / sqrtf((float)v[j] + 1.0f);
    int s = v[0] + v[1] + v[2] + v[3];
    tmp[t] = s;
    __syncthreads();
    for (int off = 1; off < 256; off <<= 1) {
        int x = (t >= off) ? tmp[t - off] : 0;
        __syncthreads();
        tmp[t] += x;
        __syncthreads();
    }
    int run = tmp[t] - s;
#pragma unroll
    for (int j = 0; j < 4; ++j) {
        if (base + j < n) excl[base + j] = run;
        run += v[j];
    }
    if (t == 255) bsum[b] = tmp[255];
}

// ---- scan 2+3 + graph boundaries + W pre-split (trailing blocks) ----
__global__ __launch_bounds__(256) void k_scan23(const int* __restrict__ excl,
                                                const int* __restrict__ bsum,
                                                const int* __restrict__ batch,
                                                int* __restrict__ rowstart,
                                                int* __restrict__ gstart,
                                                const float* __restrict__ W1,
                                                const float* __restrict__ W2,
                                                unsigned short* __restrict__ W1hi,
                                                unsigned short* __restrict__ W1lo,
                                                unsigned short* __restrict__ W2hi,
                                                unsigned short* __restrict__ W2lo,
                                                int n, int E, int nb, int nblk) {
    const int t = threadIdx.x;
    if (blockIdx.x >= nblk) {  // W-conversion blocks
        int idx = (blockIdx.x - nblk) * 256 + t;
        if (idx < 128 * 64) {
            int k = idx >> 6, c = idx & 63;
            float f = W1[idx];
            unsigned hb = bfbits(f);
            W1hi[c * 128 + k] = (unsigned short)hb;
            W1lo[c * 128 + k] = (unsigned short)bfbits(f - bfval(hb));
        } else if (idx < 128 * 64 + 64 * 64) {
            int i2 = idx - 128 * 64;
            int k = i2 >> 6, c = i2 & 63;
            float f = W2[i2];
            unsigned hb = bfbits(f);
            W2hi[c * 64 + k] = (unsigned short)hb;
            W2lo[c * 64 + k] = (unsigned short)bfbits(f - bfval(hb));
        }
        return;
    }
    __shared__ int bs[256];
    __shared__ int pre;
    if (t < nb) bs[t] = bsum[t];
    __syncthreads();
    if (t == 0) {
        int seg = (blockIdx.x * 256) >> 10;
        int s = 0;
        for (int b = 0; b < seg; ++b) s += bs[b];
        pre = s;
    }
    __syncthreads();
    int i = blockIdx.x * 256 + t;
    if (i < n) {
        rowstart[i] = excl[i] + pre;
        int bi = batch[i];
        int bp = (i == 0) ? -1 : batch[i - 1];
        for (int g = bp + 1; g <= bi; ++g) gstart[g] = i;
        if (i == n - 1)
            for (int g = bi + 1; g <= NG; ++g) gstart[g] = n;
    }
    if (i == 0) rowstart[n] = E;
}

// ---- CSR fill (atomic-free) ----
__global__ void k_fill(const int* __restrict__ src, const int* __restrict__ dst,
                       const int* __restrict__ rank, const int* __restrict__ rowstart,
                       int* __restrict__ col, int E) {
    int e = blockIdx.x * blockDim.x + threadIdx.x;
    if (e >= E) return;
    col[rowstart[dst[e]] + rank[e]] = src[e];
}

// ---- MFMA GEMM (layer 1): out = (A[n,128] @ W) * dinv[row], 32 rows/wave ----
template<int K>
__global__ __launch_bounds__(256) void k_gemm_mfma(const float* __restrict__ A,
                                                   const unsigned short* __restrict__ Whi,
                                                   const unsigned short* __restrict__ Wlo,
                                                   const float* __restrict__ dinv,
                                                   float* __restrict__ out, int n) {
    const int wave = threadIdx.x >> 6, lane = threadIdx.x & 63;
    const int ntile2 = (n + 31) >> 5;
    const int tile2 = blockIdx.x * 4 + wave;
    if (tile2 >= ntile2) return;
    const int lrow = lane & 15;
    const int kgrp = lane >> 4;
    const int r0 = tile2 * 32 + lrow;
    const int r1 = r0 + 16;

    f32x4 acc0[4], acc1[4];
#pragma unroll
    for (int ct = 0; ct < 4; ++ct) {
        acc0[ct] = (f32x4){0.f, 0.f, 0.f, 0.f};
        acc1[ct] = (f32x4){0.f, 0.f, 0.f, 0.f};
    }

#pragma unroll
    for (int s = 0; s < K / 32; ++s) {
        float a0[8], a1[8];
        {
            const float* p0 = A + (size_t)r0 * K + s * 32 + kgrp * 8;
            const float* p1 = A + (size_t)r1 * K + s * 32 + kgrp * 8;
            float4 u0, u1, w0, w1;
            if (r0 < n) { u0 = *(const float4*)p0; u1 = *(const float4*)(p0 + 4); }
            else { u0 = make_float4(0.f,0.f,0.f,0.f); u1 = u0; }
            if (r1 < n) { w0 = *(const float4*)p1; w1 = *(const float4*)(p1 + 4); }
            else { w0 = make_float4(0.f,0.f,0.f,0.f); w1 = w0; }
            a0[0]=u0.x; a0[1]=u0.y; a0[2]=u0.z; a0[3]=u0.w;
            a0[4]=u1.x; a0[5]=u1.y; a0[6]=u1.z; a0[7]=u1.w;
            a1[0]=w0.x; a1[1]=w0.y; a1[2]=w0.z; a1[3]=w0.w;
            a1[4]=w1.x; a1[5]=w1.y; a1[6]=w1.z; a1[7]=w1.w;
        }
        bf16x8 ahi0, alo0, ahi1, alo1;
#pragma unroll
        for (int e = 0; e < 8; ++e) {
            unsigned hb0 = bfbits(a0[e]);
            ahi0[e] = (short)hb0;
            alo0[e] = (short)bfbits(a0[e] - bfval(hb0));
            unsigned hb1 = bfbits(a1[e]);
            ahi1[e] = (short)hb1;
            alo1[e] = (short)bfbits(a1[e] - bfval(hb1));
        }
#pragma unroll
        for (int ct = 0; ct < 4; ++ct) {
            const size_t wo = (size_t)(ct * 16 + lrow) * K + s * 32 + kgrp * 8;
            bf16x8 whi = *(const bf16x8*)(Whi + wo);
            bf16x8 wlo = *(const bf16x8*)(Wlo + wo);
            acc0[ct] = __builtin_amdgcn_mfma_f32_16x16x32_bf16(ahi0, whi, acc0[ct], 0, 0, 0);
            acc0[ct] = __builtin_amdgcn_mfma_f32_16x16x32_bf16(alo0, whi, acc0[ct], 0, 0, 0);
            acc0[ct] = __builtin_amdgcn_mfma_f32_16x16x32_bf16(ahi0, wlo, acc0[ct], 0, 0, 0);
            acc1[ct] = __builtin_amdgcn_mfma_f32_16x16x32_bf16(ahi1, whi, acc1[ct], 0, 0, 0);
            acc1[ct] = __builtin_amdgcn_mfma_f32_16x16x32_bf16(alo1, whi, acc1[ct], 0, 0, 0);
            acc1[ct] = __builtin_amdgcn_mfma_f32_16x16x32_bf16(ahi1, wlo, acc1[ct], 0, 0, 0);
        }
    }

#pragma unroll
    for (int r = 0; r < 4; ++r) {
        int o0 = tile2 * 32 + kgrp * 4 + r;
        if (o0 < n) {
            float dv = dinv[o0];
#pragma unroll
            for (int ct = 0; ct < 4; ++ct)
                out[(size_t)o0 * HID + ct * 16 + lrow] = acc0[ct][r] * dv;
        }
        int o1 = o0 + 16;
        if (o1 < n) {
            float dv = dinv[o1];
#pragma unroll
            for (int ct = 0; ct < 4; ++ct)
                out[(size_t)o1 * HID + ct * 16 + lrow] = acc1[ct][r] * dv;
        }
    }
}

// ---- FUSED: gather layer-1 (relu into LDS) + gemm layer-2 (MFMA from LDS)
// Block: 512 threads = 8 waves, 32 nodes. Gather: wave w -> nodes w*4..w*4+3,
// dual 8-deep pipelines. GEMM: wave w -> (rowhalf=w>>2, coltile=w&3).
// outB[row,:] = (relu(b1 + dinv*(hs_self + sum hs_nb)) @ W2) * dinv[row]
__global__ __launch_bounds__(512) void k_gather_gemm2(const float* __restrict__ hs,
                                                      const int* __restrict__ rowstart,
                                                      const int* __restrict__ col,
                                                      const float* __restrict__ dinv,
                                                      const float* __restrict__ bias,
                                                      const unsigned short* __restrict__ Whi,
                                                      const unsigned short* __restrict__ Wlo,
                                                      float* __restrict__ outB, int n) {
    __shared__ float Ash[32][68];  // +4 pad: ds_read_b128 ~2-way (free)
    const int wave = threadIdx.x >> 6, lane = threadIdx.x & 63;
    const int nodebase = blockIdx.x * 32 + wave * 4;
    const float bl = bias[lane];

    // ---- gather phase: 4 nodes per wave (2 dual-pipeline iterations) ----
#pragma unroll
    for (int p = 0; p < 2; ++p) {
        const int n0 = nodebase + 2 * p;
        const int n1 = n0 + 1;
        const bool has0 = (n0 < n), has1 = (n1 < n);
        float di0 = 0.f, acc0 = 0.f, acc0b = 0.f;
        float di1 = 0.f, acc1 = 0.f, acc1b = 0.f;
        int j0 = 0, e0 = 0, j1 = 0, e1 = 0;
        if (has0) {
            di0 = dinv[n0];
            acc0 = hs[(size_t)n0 * HID + lane];
            j0 = rowstart[n0]; e0 = rowstart[n0 + 1];
        }
        if (has1) {
            di1 = dinv[n1];
            acc1 = hs[(size_t)n1 * HID + lane];
            j1 = e0; e1 = rowstart[n1 + 1];
        }
        while (e0 - j0 >= 8 && e1 - j1 >= 8) {
            const int jb0 = __builtin_amdgcn_readfirstlane(j0);
            const int jb1 = __builtin_amdgcn_readfirstlane(j1);
            int c0[8], c1[8];
#pragma unroll
            for (int t = 0; t < 8; ++t) c0[t] = col[jb0 + t];
#pragma unroll
            for (int t = 0; t < 8; ++t) c1[t] = col[jb1 + t];
            float v0[8], v1[8];
#pragma unroll
            for (int t = 0; t < 8; ++t) v0[t] = hs[(size_t)c0[t] * HID + lane];
#pragma unroll
            for (int t = 0; t < 8; ++t) v1[t] = hs[(size_t)c1[t] * HID + lane];
#pragma unroll
            for (int t = 0; t < 8; ++t) { if (t & 1) acc0b += v0[t]; else acc0 += v0[t]; }
#pragma unroll
            for (int t = 0; t < 8; ++t) { if (t & 1) acc1b += v1[t]; else acc1 += v1[t]; }
            j0 += 8; j1 += 8;
        }
        while (e0 - j0 >= 8) {
            const int jb = __builtin_amdgcn_readfirstlane(j0);
            int c[8];
#pragma unroll
            for (int t = 0; t < 8; ++t) c[t] = col[jb + t];
            float v[8];
#pragma unroll
            for (int t = 0; t < 8; ++t) v[t] = hs[(size_t)c[t] * HID + lane];
#pragma unroll
            for (int t = 0; t < 8; ++t) { if (t & 1) acc0b += v[t]; else acc0 += v[t]; }
            j0 += 8;
        }
        while (e1 - j1 >= 8) {
            const int jb = __builtin_amdgcn_readfirstlane(j1);
            int c[8];
#pragma unroll
            for (int t = 0; t < 8; ++t) c[t] = col[jb + t];
            float v[8];
#pragma unroll
            for (int t = 0; t < 8; ++t) v[t] = hs[(size_t)c[t] * HID + lane];
#pragma unroll
            for (int t = 0; t < 8; ++t) { if (t & 1) acc1b += v[t]; else acc1 += v[t]; }
            j1 += 8;
        }
        for (; j0 + 1 < e0; j0 += 2) {
            acc0  += hs[(size_t)col[j0] * HID + lane];
            acc0b += hs[(size_t)col[j0 + 1] * HID + lane];
        }
        if (j0 < e0) acc0 += hs[(size_t)col[j0] * HID + lane];
        for (; j1 + 1 < e1; j1 += 2) {
            acc1  += hs[(size_t)col[j1] * HID + lane];
            acc1b += hs[(size_t)col[j1 + 1] * HID + lane];
        }
        if (j1 < e1) acc1 += hs[(size_t)col[j1] * HID + lane];

        Ash[wave * 4 + 2 * p][lane]     = has0 ? fmaxf(fmaf(acc0 + acc0b, di0, bl), 0.f) : 0.f;
        Ash[wave * 4 + 2 * p + 1][lane] = has1 ? fmaxf(fmaf(acc1 + acc1b, di1, bl), 0.f) : 0.f;
    }
    __syncthreads();

    // ---- gemm phase (K=64): wave -> (rowhalf, coltile) 16x16 unit ----
    const int rowhalf = wave >> 2, ct = wave & 3;
    const int lrow = lane & 15;
    const int kgrp = lane >> 4;
    f32x4 acc = (f32x4){0.f, 0.f, 0.f, 0.f};
#pragma unroll
    for (int s = 0; s < 2; ++s) {
        const float* ap = &Ash[rowhalf * 16 + lrow][s * 32 + kgrp * 8];
        float4 u0 = *(const float4*)ap;
        float4 u1 = *(const float4*)(ap + 4);
        float av[8] = {u0.x, u0.y, u0.z, u0.w, u1.x, u1.y, u1.z, u1.w};
        bf16x8 ahi, alo;
#pragma unroll
        for (int e = 0; e < 8; ++e) {
            unsigned hb = bfbits(av[e]);
            ahi[e] = (short)hb;
            alo[e] = (short)bfbits(av[e] - bfval(hb));
        }
        const size_t wo = (size_t)(ct * 16 + lrow) * 64 + s * 32 + kgrp * 8;
        bf16x8 whi = *(const bf16x8*)(Whi + wo);
        bf16x8 wlo = *(const bf16x8*)(Wlo + wo);
        acc = __builtin_amdgcn_mfma_f32_16x16x32_bf16(ahi, whi, acc, 0, 0, 0);
        acc = __builtin_amdgcn_mfma_f32_16x16x32_bf16(alo, whi, acc, 0, 0, 0);
        acc = __builtin_amdgcn_mfma_f32_16x16x32_bf16(ahi, wlo, acc, 0, 0, 0);
    }
#pragma unroll
    for (int r = 0; r < 4; ++r) {
        int orow = blockIdx.x * 32 + rowhalf * 16 + kgrp * 4 + r;
        if (orow < n)
            outB[(size_t)orow * HID + ct * 16 + lrow] = acc[r] * dinv[orow];
    }
}

// ---- CSR gather (layer 2): 2 nodes/wave, dual 8-deep, relu fused ----
__global__ __launch_bounds__(256) void k_gather(const float* __restrict__ hs,
                                                const int* __restrict__ rowstart,
                                                const int* __restrict__ col,
                                                const float* __restrict__ dinv,
                                                const float* __restrict__ bias,
                                                float* __restrict__ out, int n) {
    const int wave = threadIdx.x >> 6, lane = threadIdx.x & 63;
    const int n0 = blockIdx.x * 8 + wave * 2;
    if (n0 >= n) return;
    const int n1 = n0 + 1;
    const bool has1 = (n1 < n);
    const float bl = bias[lane];

    float di0 = dinv[n0];
    float acc0 = hs[(size_t)n0 * HID + lane], acc0b = 0.f;
    int j0 = rowstart[n0], e0 = rowstart[n0 + 1];
    float di1 = 0.f, acc1 = 0.f, acc1b = 0.f;
    int j1 = 0, e1 = 0;
    if (has1) {
        di1 = dinv[n1];
        acc1 = hs[(size_t)n1 * HID + lane];
        j1 = e0; e1 = rowstart[n1 + 1];
    }
    while (e0 - j0 >= 8 && e1 - j1 >= 8) {
        const int jb0 = __builtin_amdgcn_readfirstlane(j0);
        const int jb1 = __builtin_amdgcn_readfirstlane(j1);
        int c0[8], c1[8];
#pragma unroll
        for (int t = 0; t < 8; ++t) c0[t] = col[jb0 + t];
#pragma unroll
        for (int t = 0; t < 8; ++t) c1[t] = col[jb1 + t];
        float v0[8], v1[8];
#pragma unroll
        for (int t = 0; t < 8; ++t) v0[t] = hs[(size_t)c0[t] * HID + lane];
#pragma unroll
        for (int t = 0; t < 8; ++t) v1[t] = hs[(size_t)c1[t] * HID + lane];
#pragma unroll
        for (int t = 0; t < 8; ++t) { if (t & 1) acc0b += v0[t]; else acc0 += v0[t]; }
#pragma unroll
        for (int t = 0; t < 8; ++t) { if (t & 1) acc1b += v1[t]; else acc1 += v1[t]; }
        j0 += 8; j1 += 8;
    }
    while (e0 - j0 >= 8) {
        const int jb = __builtin_amdgcn_readfirstlane(j0);
        int c[8];
#pragma unroll
        for (int t = 0; t < 8; ++t) c[t] = col[jb + t];
        float v[8];
#pragma unroll
        for (int t = 0; t < 8; ++t) v[t] = hs[(size_t)c[t] * HID + lane];
#pragma unroll
        for (int t = 0; t < 8; ++t) { if (t & 1) acc0b += v[t]; else acc0 += v[t]; }
        j0 += 8;
    }
    while (e1 - j1 >= 8) {
        const int jb = __builtin_amdgcn_readfirstlane(j1);
        int c[8];
#pragma unroll
        for (int t = 0; t < 8; ++t) c[t] = col[jb + t];
        float v[8];
#pragma unroll
        for (int t = 0; t < 8; ++t) v[t] = hs[(size_t)c[t] * HID + lane];
#pragma unroll
        for (int t = 0; t < 8; ++t) { if (t & 1) acc1b += v[t]; else acc1 += v[t]; }
        j1 += 8;
    }
    for (; j0 + 1 < e0; j0 += 2) {
        acc0  += hs[(size_t)col[j0] * HID + lane];
        acc0b += hs[(size_t)col[j0 + 1] * HID + lane];
    }
    if (j0 < e0) acc0 += hs[(size_t)col[j0] * HID + lane];
    for (; j1 + 1 < e1; j1 += 2) {
        acc1  += hs[(size_t)col[j1] * HID + lane];
        acc1b += hs[(size_t)col[j1 + 1] * HID + lane];
    }
    if (j1 < e1) acc1 += hs[(size_t)col[j1] * HID + lane];

    out[(size_t)n0 * HID + lane] = fmaxf(fmaf(acc0 + acc0b, di0, bl), 0.f);
    if (has1)
        out[(size_t)n1 * HID + lane] = fmaxf(fmaf(acc1 + acc1b, di1, bl), 0.f);
}

// ---- fused mean-pool + MLP head ----
__global__ __launch_bounds__(512) void k_poolhead(const float* __restrict__ h,
                                                  const int* __restrict__ gstart,
                                                  const float* __restrict__ Wc1,
                                                  const float* __restrict__ bc1,
                                                  const float* __restrict__ Wc2,
                                                  const float* __restrict__ bc2,
                                                  float* __restrict__ outp, int n) {
    const int g = blockIdx.x;
    const int lo = gstart[g], lo2 = gstart[g + 1];
    const int t = threadIdx.x;
    const int rg = t >> 4;
    const int c4 = (t & 15) * 4;
    float4 acc = make_float4(0.f, 0.f, 0.f, 0.f);
    for (int r = lo + rg; r < lo2; r += 32) {
        float4 v = *(const float4*)(h + (size_t)r * HID + c4);
        acc.x += v.x; acc.y += v.y; acc.z += v.z; acc.w += v.w;
    }
    __shared__ float4 red[32][16];
    __shared__ float gmv[HID];
    __shared__ float zs[32];
    red[rg][t & 15] = acc;
    __syncthreads();
    if (t < 16) {
        float4 s = red[0][t];
#pragma unroll
        for (int g2 = 1; g2 < 32; ++g2) {
            float4 v = red[g2][t];
            s.x += v.x; s.y += v.y; s.z += v.z; s.w += v.w;
        }
        float inv = 1.0f / fmaxf((float)(lo2 - lo), 1.0f);
        gmv[t * 4 + 0] = s.x * inv; gmv[t * 4 + 1] = s.y * inv;
        gmv[t * 4 + 2] = s.z * inv; gmv[t * 4 + 3] = s.w * inv;
    }
    __syncthreads();
    if (t < 32) {
        float z = bc1[t];
#pragma unroll 8
        for (int k = 0; k < HID; ++k) z = fmaf(gmv[k], Wc1[k * 32 + t], z);
        zs[t] = fmaxf(z, 0.f) * Wc2[t];
    }
    __syncthreads();
    if (t == 0) {
        float o = bc2[0];
#pragma unroll
        for (int j = 0; j < 32; ++j) o += zs[j];
        outp[g] = o;
    }
}

extern "C" void kernel_launch(void* const* d_in, const int* in_sizes, int n_in,
                              void* d_out, int out_size, void* d_ws, size_t ws_size,
                              hipStream_t stream) {
    const float* x    = (const float*)d_in[0];
    const int*   ei   = (const int*)d_in[1];
    const int*   batch= (const int*)d_in[2];
    const float* W1   = (const float*)d_in[3];
    const float* b1   = (const float*)d_in[4];
    const float* W2   = (const float*)d_in[5];
    const float* b2   = (const float*)d_in[6];
    const float* Wc1  = (const float*)d_in[7];
    const float* bc1  = (const float*)d_in[8];
    const float* Wc2  = (const float*)d_in[9];
    const float* bc2  = (const float*)d_in[10];

    const int E = in_sizes[1] / 2;
    const int n = in_sizes[0] / 128;   // 50000 nodes
    const int* srcp = ei;
    const int* dstp = ei + E;
    const int nb = (n + 1023) / 1024;

    char* ws = (char*)d_ws;
    auto alloc = [&](size_t bytes) {
        char* p = ws;
        ws += (bytes + 255) & ~(size_t)255;
        return p;
    };
    int*   deg      = (int*)  alloc((size_t)n * 4);
    float* dinv     = (float*)alloc((size_t)n * 4);
    int*   excl     = (int*)  alloc((size_t)n * 4);
    int*   bsum     = (int*)  alloc((size_t)nb * 4);
    int*   rowstart = (int*)  alloc((size_t)(n + 1) * 4);
    int*   gstart   = (int*)  alloc((size_t)(NG + 1) * 4);
    int*   rank     = (int*)  alloc((size_t)E * 4);
    int*   col      = (int*)  alloc((size_t)E * 4);
    float* bufA     = (float*)alloc((size_t)n * HID * 4);
    float* bufB     = (float*)alloc((size_t)n * HID * 4);
    unsigned short* W1hi = (unsigned short*)alloc(128 * 64 * 2);
    unsigned short* W1lo = (unsigned short*)alloc(128 * 64 * 2);
    unsigned short* W2hi = (unsigned short*)alloc(64 * 64 * 2);
    unsigned short* W2lo = (unsigned short*)alloc(64 * 64 * 2);

    hipMemsetAsync(deg, 0, (size_t)n * 4, stream);

    const int nblk = (n + 255) / 256;
    const int wblk = (128 * 64 + 64 * 64 + 255) / 256;

    k_deg   <<<(E + 255) / 256, 256, 0, stream>>>(dstp, E, deg, rank);
    k_scan1 <<<nb, 256, 0, stream>>>(deg, excl, bsum, dinv, n);
    k_scan23<<<nblk + wblk, 256, 0, stream>>>(excl, bsum, batch, rowstart, gstart,
                                              W1, W2, W1hi, W1lo, W2hi, W2lo,
                                              n, E, nb, nblk);
    k_fill  <<<(E + 255) / 256, 256, 0, stream>>>(srcp, dstp, rank, rowstart, col, E);

    const int mblocks = ((n + 31) / 32 + 3) / 4;

    // Layer 1 GEMM, then fused {gather1 + layer-2 GEMM}, then gather2
    k_gemm_mfma<128><<<mblocks, 256, 0, stream>>>(x, W1hi, W1lo, dinv, bufA, n);
    k_gather_gemm2<<<(n + 31) / 32, 512, 0, stream>>>(bufA, rowstart, col, dinv, b1,
                                                      W2hi, W2lo, bufB, n);
    k_gather<<<(n + 7) / 8, 256, 0, stream>>>(bufB, rowstart, col, dinv, b2, bufA, n);

    // Fused pool + head
    k_poolhead<<<NG, 512, 0, stream>>>(bufA, gstart, Wc1, bc1, Wc2, bc2, (float*)d_out, n);
}

// Round 10
// 162.546 us; speedup vs baseline: 9.8332x; 1.0006x over previous
//
#include <hip/hip_runtime.h>
#include <math.h>

#define NG 64
#define HID 64

typedef __attribute__((ext_vector_type(8))) short bf16x8;
typedef __attribute__((ext_vector_type(4))) float f32x4;

// RNE f32 -> bf16 bit helpers (data finite; no NaN handling needed)
__device__ __forceinline__ unsigned int bfbits(float f) {
    unsigned int u = __float_as_uint(f);
    return (u + 0x7FFFu + ((u >> 16) & 1u)) >> 16;
}
__device__ __forceinline__ float bfval(unsigned int bits) {
    return __uint_as_float(bits << 16);
}

// ---- zero deg (replaces runtime fillBuffer: 43us -> ~2us) ----
__global__ void k_zero(int4* __restrict__ p, int n4) {
    int i = blockIdx.x * blockDim.x + threadIdx.x;
    if (i < n4) p[i] = make_int4(0, 0, 0, 0);
}

// ---- degree count + slot rank (in-degree from edges; self-loop in dinv) ----
__global__ void k_deg(const int* __restrict__ dst, int E,
                      int* __restrict__ deg, int* __restrict__ rank) {
    int i = blockIdx.x * blockDim.x + threadIdx.x;
    if (i < E) rank[i] = atomicAdd(deg + dst[i], 1);
}

// ---- scan level 1 + dinv ----
__global__ __launch_bounds__(256) void k_scan1(const int* __restrict__ deg,
                                               int* __restrict__ excl,
                                               int* __restrict__ bsum,
                                               float* __restrict__ dinv, int n) {
    __shared__ int tmp[256];
    int b = blockIdx.x, t = threadIdx.x;
    int base = b * 1024 + t * 4;
    int v[4];
#pragma unroll
    for (int j = 0; j < 4; ++j) v[j] = (base + j < n) ? deg[base + j] : 0;
#pragma unroll
    for (int j = 0; j < 4; ++j)
        if (base + j < n) dinv[base + j] = 1.0f / sqrtf((float)v[j] + 1.0f);
    int s = v[0] + v[1] + v[2] + v[3];
    tmp[t] = s;
    __syncthreads();
    for (int off = 1; off < 256; off <<= 1) {
        int x = (t >= off) ? tmp[t - off] : 0;
        __syncthreads();
        tmp[t] += x;
        __syncthreads();
    }
    int run = tmp[t] - s;
#pragma unroll
    for (int j = 0; j < 4; ++j) {
        if (base + j < n) excl[base + j] = run;
        run += v[j];
    }
    if (t == 255) bsum[b] = tmp[255];
}

// ---- scan 2+3 + graph boundaries + W pre-split (trailing blocks) ----
__global__ __launch_bounds__(256) void k_scan23(const int* __restrict__ excl,
                                                const int* __restrict__ bsum,
                                                const int* __restrict__ batch,
                                                int* __restrict__ rowstart,
                                                int* __restrict__ gstart,
                                                const float* __restrict__ W1,
                                                const float* __restrict__ W2,
                                                unsigned short* __restrict__ W1hi,
                                                unsigned short* __restrict__ W1lo,
                                                unsigned short* __restrict__ W2hi,
                                                unsigned short* __restrict__ W2lo,
                                                int n, int E, int nb, int nblk) {
    const int t = threadIdx.x;
    if (blockIdx.x >= nblk) {  // W-conversion blocks
        int idx = (blockIdx.x - nblk) * 256 + t;
        if (idx < 128 * 64) {
            int k = idx >> 6, c = idx & 63;
            float f = W1[idx];
            unsigned hb = bfbits(f);
            W1hi[c * 128 + k] = (unsigned short)hb;
            W1lo[c * 128 + k] = (unsigned short)bfbits(f - bfval(hb));
        } else if (idx < 128 * 64 + 64 * 64) {
            int i2 = idx - 128 * 64;
            int k = i2 >> 6, c = i2 & 63;
            float f = W2[i2];
            unsigned hb = bfbits(f);
            W2hi[c * 64 + k] = (unsigned short)hb;
            W2lo[c * 64 + k] = (unsigned short)bfbits(f - bfval(hb));
        }
        return;
    }
    __shared__ int bs[256];
    __shared__ int pre;
    if (t < nb) bs[t] = bsum[t];
    __syncthreads();
    if (t == 0) {
        int seg = (blockIdx.x * 256) >> 10;
        int s = 0;
        for (int b = 0; b < seg; ++b) s += bs[b];
        pre = s;
    }
    __syncthreads();
    int i = blockIdx.x * 256 + t;
    if (i < n) {
        rowstart[i] = excl[i] + pre;
        int bi = batch[i];
        int bp = (i == 0) ? -1 : batch[i - 1];
        for (int g = bp + 1; g <= bi; ++g) gstart[g] = i;
        if (i == n - 1)
            for (int g = bi + 1; g <= NG; ++g) gstart[g] = n;
    }
    if (i == 0) rowstart[n] = E;
}

// ---- CSR fill (atomic-free) ----
__global__ void k_fill(const int* __restrict__ src, const int* __restrict__ dst,
                       const int* __restrict__ rank, const int* __restrict__ rowstart,
                       int* __restrict__ col, int E) {
    int e = blockIdx.x * blockDim.x + threadIdx.x;
    if (e >= E) return;
    col[rowstart[dst[e]] + rank[e]] = src[e];
}

// ---- MFMA GEMM (layer 1): out = (A[n,128] @ W) * dinv[row], 32 rows/wave ----
template<int K>
__global__ __launch_bounds__(256) void k_gemm_mfma(const float* __restrict__ A,
                                                   const unsigned short* __restrict__ Whi,
                                                   const unsigned short* __restrict__ Wlo,
                                                   const float* __restrict__ dinv,
                                                   float* __restrict__ out, int n) {
    const int wave = threadIdx.x >> 6, lane = threadIdx.x & 63;
    const int ntile2 = (n + 31) >> 5;
    const int tile2 = blockIdx.x * 4 + wave;
    if (tile2 >= ntile2) return;
    const int lrow = lane & 15;
    const int kgrp = lane >> 4;
    const int r0 = tile2 * 32 + lrow;
    const int r1 = r0 + 16;

    f32x4 acc0[4], acc1[4];
#pragma unroll
    for (int ct = 0; ct < 4; ++ct) {
        acc0[ct] = (f32x4){0.f, 0.f, 0.f, 0.f};
        acc1[ct] = (f32x4){0.f, 0.f, 0.f, 0.f};
    }

#pragma unroll
    for (int s = 0; s < K / 32; ++s) {
        float a0[8], a1[8];
        {
            const float* p0 = A + (size_t)r0 * K + s * 32 + kgrp * 8;
            const float* p1 = A + (size_t)r1 * K + s * 32 + kgrp * 8;
            float4 u0, u1, w0, w1;
            if (r0 < n) { u0 = *(const float4*)p0; u1 = *(const float4*)(p0 + 4); }
            else { u0 = make_float4(0.f,0.f,0.f,0.f); u1 = u0; }
            if (r1 < n) { w0 = *(const float4*)p1; w1 = *(const float4*)(p1 + 4); }
            else { w0 = make_float4(0.f,0.f,0.f,0.f); w1 = w0; }
            a0[0]=u0.x; a0[1]=u0.y; a0[2]=u0.z; a0[3]=u0.w;
            a0[4]=u1.x; a0[5]=u1.y; a0[6]=u1.z; a0[7]=u1.w;
            a1[0]=w0.x; a1[1]=w0.y; a1[2]=w0.z; a1[3]=w0.w;
            a1[4]=w1.x; a1[5]=w1.y; a1[6]=w1.z; a1[7]=w1.w;
        }
        bf16x8 ahi0, alo0, ahi1, alo1;
#pragma unroll
        for (int e = 0; e < 8; ++e) {
            unsigned hb0 = bfbits(a0[e]);
            ahi0[e] = (short)hb0;
            alo0[e] = (short)bfbits(a0[e] - bfval(hb0));
            unsigned hb1 = bfbits(a1[e]);
            ahi1[e] = (short)hb1;
            alo1[e] = (short)bfbits(a1[e] - bfval(hb1));
        }
#pragma unroll
        for (int ct = 0; ct < 4; ++ct) {
            const size_t wo = (size_t)(ct * 16 + lrow) * K + s * 32 + kgrp * 8;
            bf16x8 whi = *(const bf16x8*)(Whi + wo);
            bf16x8 wlo = *(const bf16x8*)(Wlo + wo);
            acc0[ct] = __builtin_amdgcn_mfma_f32_16x16x32_bf16(ahi0, whi, acc0[ct], 0, 0, 0);
            acc0[ct] = __builtin_amdgcn_mfma_f32_16x16x32_bf16(alo0, whi, acc0[ct], 0, 0, 0);
            acc0[ct] = __builtin_amdgcn_mfma_f32_16x16x32_bf16(ahi0, wlo, acc0[ct], 0, 0, 0);
            acc1[ct] = __builtin_amdgcn_mfma_f32_16x16x32_bf16(ahi1, whi, acc1[ct], 0, 0, 0);
            acc1[ct] = __builtin_amdgcn_mfma_f32_16x16x32_bf16(alo1, whi, acc1[ct], 0, 0, 0);
            acc1[ct] = __builtin_amdgcn_mfma_f32_16x16x32_bf16(ahi1, wlo, acc1[ct], 0, 0, 0);
        }
    }

#pragma unroll
    for (int r = 0; r < 4; ++r) {
        int o0 = tile2 * 32 + kgrp * 4 + r;
        if (o0 < n) {
            float dv = dinv[o0];
#pragma unroll
            for (int ct = 0; ct < 4; ++ct)
                out[(size_t)o0 * HID + ct * 16 + lrow] = acc0[ct][r] * dv;
        }
        int o1 = o0 + 16;
        if (o1 < n) {
            float dv = dinv[o1];
#pragma unroll
            for (int ct = 0; ct < 4; ++ct)
                out[(size_t)o1 * HID + ct * 16 + lrow] = acc1[ct][r] * dv;
        }
    }
}

// ---- FUSED: gather layer-1 (relu into LDS) + gemm layer-2 (MFMA from LDS) ----
__global__ __launch_bounds__(512) void k_gather_gemm2(const float* __restrict__ hs,
                                                      const int* __restrict__ rowstart,
                                                      const int* __restrict__ col,
                                                      const float* __restrict__ dinv,
                                                      const float* __restrict__ bias,
                                                      const unsigned short* __restrict__ Whi,
                                                      const unsigned short* __restrict__ Wlo,
                                                      float* __restrict__ outB, int n) {
    __shared__ float Ash[32][68];  // +4 pad: ds_read_b128 ~2-way (free)
    const int wave = threadIdx.x >> 6, lane = threadIdx.x & 63;
    const int nodebase = blockIdx.x * 32 + wave * 4;
    const float bl = bias[lane];

    // ---- gather phase: 4 nodes per wave (2 dual-pipeline iterations) ----
#pragma unroll
    for (int p = 0; p < 2; ++p) {
        const int n0 = nodebase + 2 * p;
        const int n1 = n0 + 1;
        const bool has0 = (n0 < n), has1 = (n1 < n);
        float di0 = 0.f, acc0 = 0.f, acc0b = 0.f;
        float di1 = 0.f, acc1 = 0.f, acc1b = 0.f;
        int j0 = 0, e0 = 0, j1 = 0, e1 = 0;
        if (has0) {
            di0 = dinv[n0];
            acc0 = hs[(size_t)n0 * HID + lane];
            j0 = rowstart[n0]; e0 = rowstart[n0 + 1];
        }
        if (has1) {
            di1 = dinv[n1];
            acc1 = hs[(size_t)n1 * HID + lane];
            j1 = e0; e1 = rowstart[n1 + 1];
        }
        while (e0 - j0 >= 8 && e1 - j1 >= 8) {
            const int jb0 = __builtin_amdgcn_readfirstlane(j0);
            const int jb1 = __builtin_amdgcn_readfirstlane(j1);
            int c0[8], c1[8];
#pragma unroll
            for (int t = 0; t < 8; ++t) c0[t] = col[jb0 + t];
#pragma unroll
            for (int t = 0; t < 8; ++t) c1[t] = col[jb1 + t];
            float v0[8], v1[8];
#pragma unroll
            for (int t = 0; t < 8; ++t) v0[t] = hs[(size_t)c0[t] * HID + lane];
#pragma unroll
            for (int t = 0; t < 8; ++t) v1[t] = hs[(size_t)c1[t] * HID + lane];
#pragma unroll
            for (int t = 0; t < 8; ++t) { if (t & 1) acc0b += v0[t]; else acc0 += v0[t]; }
#pragma unroll
            for (int t = 0; t < 8; ++t) { if (t & 1) acc1b += v1[t]; else acc1 += v1[t]; }
            j0 += 8; j1 += 8;
        }
        while (e0 - j0 >= 8) {
            const int jb = __builtin_amdgcn_readfirstlane(j0);
            int c[8];
#pragma unroll
            for (int t = 0; t < 8; ++t) c[t] = col[jb + t];
            float v[8];
#pragma unroll
            for (int t = 0; t < 8; ++t) v[t] = hs[(size_t)c[t] * HID + lane];
#pragma unroll
            for (int t = 0; t < 8; ++t) { if (t & 1) acc0b += v[t]; else acc0 += v[t]; }
            j0 += 8;
        }
        while (e1 - j1 >= 8) {
            const int jb = __builtin_amdgcn_readfirstlane(j1);
            int c[8];
#pragma unroll
            for (int t = 0; t < 8; ++t) c[t] = col[jb + t];
            float v[8];
#pragma unroll
            for (int t = 0; t < 8; ++t) v[t] = hs[(size_t)c[t] * HID + lane];
#pragma unroll
            for (int t = 0; t < 8; ++t) { if (t & 1) acc1b += v[t]; else acc1 += v[t]; }
            j1 += 8;
        }
        for (; j0 + 1 < e0; j0 += 2) {
            acc0  += hs[(size_t)col[j0] * HID + lane];
            acc0b += hs[(size_t)col[j0 + 1] * HID + lane];
        }
        if (j0 < e0) acc0 += hs[(size_t)col[j0] * HID + lane];
        for (; j1 + 1 < e1; j1 += 2) {
            acc1  += hs[(size_t)col[j1] * HID + lane];
            acc1b += hs[(size_t)col[j1 + 1] * HID + lane];
        }
        if (j1 < e1) acc1 += hs[(size_t)col[j1] * HID + lane];

        Ash[wave * 4 + 2 * p][lane]     = has0 ? fmaxf(fmaf(acc0 + acc0b, di0, bl), 0.f) : 0.f;
        Ash[wave * 4 + 2 * p + 1][lane] = has1 ? fmaxf(fmaf(acc1 + acc1b, di1, bl), 0.f) : 0.f;
    }
    __syncthreads();

    // ---- gemm phase (K=64): wave -> (rowhalf, coltile) 16x16 unit ----
    const int rowhalf = wave >> 2, ct = wave & 3;
    const int lrow = lane & 15;
    const int kgrp = lane >> 4;
    f32x4 acc = (f32x4){0.f, 0.f, 0.f, 0.f};
#pragma unroll
    for (int s = 0; s < 2; ++s) {
        const float* ap = &Ash[rowhalf * 16 + lrow][s * 32 + kgrp * 8];
        float4 u0 = *(const float4*)ap;
        float4 u1 = *(const float4*)(ap + 4);
        float av[8] = {u0.x, u0.y, u0.z, u0.w, u1.x, u1.y, u1.z, u1.w};
        bf16x8 ahi, alo;
#pragma unroll
        for (int e = 0; e < 8; ++e) {
            unsigned hb = bfbits(av[e]);
            ahi[e] = (short)hb;
            alo[e] = (short)bfbits(av[e] - bfval(hb));
        }
        const size_t wo = (size_t)(ct * 16 + lrow) * 64 + s * 32 + kgrp * 8;
        bf16x8 whi = *(const bf16x8*)(Whi + wo);
        bf16x8 wlo = *(const bf16x8*)(Wlo + wo);
        acc = __builtin_amdgcn_mfma_f32_16x16x32_bf16(ahi, whi, acc, 0, 0, 0);
        acc = __builtin_amdgcn_mfma_f32_16x16x32_bf16(alo, whi, acc, 0, 0, 0);
        acc = __builtin_amdgcn_mfma_f32_16x16x32_bf16(ahi, wlo, acc, 0, 0, 0);
    }
#pragma unroll
    for (int r = 0; r < 4; ++r) {
        int orow = blockIdx.x * 32 + rowhalf * 16 + kgrp * 4 + r;
        if (orow < n)
            outB[(size_t)orow * HID + ct * 16 + lrow] = acc[r] * dinv[orow];
    }
}

// ---- CSR gather (layer 2): 2 nodes/wave, dual 8-deep, relu fused ----
__global__ __launch_bounds__(256) void k_gather(const float* __restrict__ hs,
                                                const int* __restrict__ rowstart,
                                                const int* __restrict__ col,
                                                const float* __restrict__ dinv,
                                                const float* __restrict__ bias,
                                                float* __restrict__ out, int n) {
    const int wave = threadIdx.x >> 6, lane = threadIdx.x & 63;
    const int n0 = blockIdx.x * 8 + wave * 2;
    if (n0 >= n) return;
    const int n1 = n0 + 1;
    const bool has1 = (n1 < n);
    const float bl = bias[lane];

    float di0 = dinv[n0];
    float acc0 = hs[(size_t)n0 * HID + lane], acc0b = 0.f;
    int j0 = rowstart[n0], e0 = rowstart[n0 + 1];
    float di1 = 0.f, acc1 = 0.f, acc1b = 0.f;
    int j1 = 0, e1 = 0;
    if (has1) {
        di1 = dinv[n1];
        acc1 = hs[(size_t)n1 * HID + lane];
        j1 = e0; e1 = rowstart[n1 + 1];
    }
    while (e0 - j0 >= 8 && e1 - j1 >= 8) {
        const int jb0 = __builtin_amdgcn_readfirstlane(j0);
        const int jb1 = __builtin_amdgcn_readfirstlane(j1);
        int c0[8], c1[8];
#pragma unroll
        for (int t = 0; t < 8; ++t) c0[t] = col[jb0 + t];
#pragma unroll
        for (int t = 0; t < 8; ++t) c1[t] = col[jb1 + t];
        float v0[8], v1[8];
#pragma unroll
        for (int t = 0; t < 8; ++t) v0[t] = hs[(size_t)c0[t] * HID + lane];
#pragma unroll
        for (int t = 0; t < 8; ++t) v1[t] = hs[(size_t)c1[t] * HID + lane];
#pragma unroll
        for (int t = 0; t < 8; ++t) { if (t & 1) acc0b += v0[t]; else acc0 += v0[t]; }
#pragma unroll
        for (int t = 0; t < 8; ++t) { if (t & 1) acc1b += v1[t]; else acc1 += v1[t]; }
        j0 += 8; j1 += 8;
    }
    while (e0 - j0 >= 8) {
        const int jb = __builtin_amdgcn_readfirstlane(j0);
        int c[8];
#pragma unroll
        for (int t = 0; t < 8; ++t) c[t] = col[jb + t];
        float v[8];
#pragma unroll
        for (int t = 0; t < 8; ++t) v[t] = hs[(size_t)c[t] * HID + lane];
#pragma unroll
        for (int t = 0; t < 8; ++t) { if (t & 1) acc0b += v[t]; else acc0 += v[t]; }
        j0 += 8;
    }
    while (e1 - j1 >= 8) {
        const int jb = __builtin_amdgcn_readfirstlane(j1);
        int c[8];
#pragma unroll
        for (int t = 0; t < 8; ++t) c[t] = col[jb + t];
        float v[8];
#pragma unroll
        for (int t = 0; t < 8; ++t) v[t] = hs[(size_t)c[t] * HID + lane];
#pragma unroll
        for (int t = 0; t < 8; ++t) { if (t & 1) acc1b += v[t]; else acc1 += v[t]; }
        j1 += 8;
    }
    for (; j0 + 1 < e0; j0 += 2) {
        acc0  += hs[(size_t)col[j0] * HID + lane];
        acc0b += hs[(size_t)col[j0 + 1] * HID + lane];
    }
    if (j0 < e0) acc0 += hs[(size_t)col[j0] * HID + lane];
    for (; j1 + 1 < e1; j1 += 2) {
        acc1  += hs[(size_t)col[j1] * HID + lane];
        acc1b += hs[(size_t)col[j1 + 1] * HID + lane];
    }
    if (j1 < e1) acc1 += hs[(size_t)col[j1] * HID + lane];

    out[(size_t)n0 * HID + lane] = fmaxf(fmaf(acc0 + acc0b, di0, bl), 0.f);
    if (has1)
        out[(size_t)n1 * HID + lane] = fmaxf(fmaf(acc1 + acc1b, di1, bl), 0.f);
}

// ---- fused mean-pool + MLP head ----
__global__ __launch_bounds__(512) void k_poolhead(const float* __restrict__ h,
                                                  const int* __restrict__ gstart,
                                                  const float* __restrict__ Wc1,
                                                  const float* __restrict__ bc1,
                                                  const float* __restrict__ Wc2,
                                                  const float* __restrict__ bc2,
                                                  float* __restrict__ outp, int n) {
    const int g = blockIdx.x;
    const int lo = gstart[g], lo2 = gstart[g + 1];
    const int t = threadIdx.x;
    const int rg = t >> 4;
    const int c4 = (t & 15) * 4;
    float4 acc = make_float4(0.f, 0.f, 0.f, 0.f);
    for (int r = lo + rg; r < lo2; r += 32) {
        float4 v = *(const float4*)(h + (size_t)r * HID + c4);
        acc.x += v.x; acc.y += v.y; acc.z += v.z; acc.w += v.w;
    }
    __shared__ float4 red[32][16];
    __shared__ float gmv[HID];
    __shared__ float zs[32];
    red[rg][t & 15] = acc;
    __syncthreads();
    if (t < 16) {
        float4 s = red[0][t];
#pragma unroll
        for (int g2 = 1; g2 < 32; ++g2) {
            float4 v = red[g2][t];
            s.x += v.x; s.y += v.y; s.z += v.z; s.w += v.w;
        }
        float inv = 1.0f / fmaxf((float)(lo2 - lo), 1.0f);
        gmv[t * 4 + 0] = s.x * inv; gmv[t * 4 + 1] = s.y * inv;
        gmv[t * 4 + 2] = s.z * inv; gmv[t * 4 + 3] = s.w * inv;
    }
    __syncthreads();
    if (t < 32) {
        float z = bc1[t];
#pragma unroll 8
        for (int k = 0; k < HID; ++k) z = fmaf(gmv[k], Wc1[k * 32 + t], z);
        zs[t] = fmaxf(z, 0.f) * Wc2[t];
    }
    __syncthreads();
    if (t == 0) {
        float o = bc2[0];
#pragma unroll
        for (int j = 0; j < 32; ++j) o += zs[j];
        outp[g] = o;
    }
}

extern "C" void kernel_launch(void* const* d_in, const int* in_sizes, int n_in,
                              void* d_out, int out_size, void* d_ws, size_t ws_size,
                              hipStream_t stream) {
    const float* x    = (const float*)d_in[0];
    const int*   ei   = (const int*)d_in[1];
    const int*   batch= (const int*)d_in[2];
    const float* W1   = (const float*)d_in[3];
    const float* b1   = (const float*)d_in[4];
    const float* W2   = (const float*)d_in[5];
    const float* b2   = (const float*)d_in[6];
    const float* Wc1  = (const float*)d_in[7];
    const float* bc1  = (const float*)d_in[8];
    const float* Wc2  = (const float*)d_in[9];
    const float* bc2  = (const float*)d_in[10];

    const int E = in_sizes[1] / 2;
    const int n = in_sizes[0] / 128;   // 50000 nodes
    const int* srcp = ei;
    const int* dstp = ei + E;
    const int nb = (n + 1023) / 1024;

    char* ws = (char*)d_ws;
    auto alloc = [&](size_t bytes) {
        char* p = ws;
        ws += (bytes + 255) & ~(size_t)255;
        return p;
    };
    int*   deg      = (int*)  alloc((size_t)((n + 3) & ~3) * 4);  // 16B-aligned for int4 zero
    float* dinv     = (float*)alloc((size_t)n * 4);
    int*   excl     = (int*)  alloc((size_t)n * 4);
    int*   bsum     = (int*)  alloc((size_t)nb * 4);
    int*   rowstart = (int*)  alloc((size_t)(n + 1) * 4);
    int*   gstart   = (int*)  alloc((size_t)(NG + 1) * 4);
    int*   rank     = (int*)  alloc((size_t)E * 4);
    int*   col      = (int*)  alloc((size_t)E * 4);
    float* bufA     = (float*)alloc((size_t)n * HID * 4);
    float* bufB     = (float*)alloc((size_t)n * HID * 4);
    unsigned short* W1hi = (unsigned short*)alloc(128 * 64 * 2);
    unsigned short* W1lo = (unsigned short*)alloc(128 * 64 * 2);
    unsigned short* W2hi = (unsigned short*)alloc(64 * 64 * 2);
    unsigned short* W2lo = (unsigned short*)alloc(64 * 64 * 2);

    const int n4 = (n + 3) / 4;
    k_zero<<<(n4 + 255) / 256, 256, 0, stream>>>((int4*)deg, n4);

    const int nblk = (n + 255) / 256;
    const int wblk = (128 * 64 + 64 * 64 + 255) / 256;

    k_deg   <<<(E + 255) / 256, 256, 0, stream>>>(dstp, E, deg, rank);
    k_scan1 <<<nb, 256, 0, stream>>>(deg, excl, bsum, dinv, n);
    k_scan23<<<nblk + wblk, 256, 0, stream>>>(excl, bsum, batch, rowstart, gstart,
                                              W1, W2, W1hi, W1lo, W2hi, W2lo,
                                              n, E, nb, nblk);
    k_fill  <<<(E + 255) / 256, 256, 0, stream>>>(srcp, dstp, rank, rowstart, col, E);

    const int mblocks = ((n + 31) / 32 + 3) / 4;

    // Layer 1 GEMM, then fused {gather1 + layer-2 GEMM}, then gather2
    k_gemm_mfma<128><<<mblocks, 256, 0, stream>>>(x, W1hi, W1lo, dinv, bufA, n);
    k_gather_gemm2<<<(n + 31) / 32, 512, 0, stream>>>(bufA, rowstart, col, dinv, b1,
                                                      W2hi, W2lo, bufB, n);
    k_gather<<<(n + 7) / 8, 256, 0, stream>>>(bufB, rowstart, col, dinv, b2, bufA, n);

    // Fused pool + head
    k_poolhead<<<NG, 512, 0, stream>>>(bufA, gstart, Wc1, bc1, Wc2, bc2, (float*)d_out, n);
}